// Round 14
// baseline (373.660 us; speedup 1.0000x reference)
//
#include <hip/hip_runtime.h>
#include <cstdint>
#include <cstddef>

#define RN 200000   // nodes per side (NU == NI)
#define NR2 400000  // both sides
#define DIM 64
#define NE 1000000  // edges per relation
#define NB_PR 391   // buckets per relation (512 rows each)
#define NBB 782     // total buckets (go: 0..390, back: 391..781)
#define ET 4096     // edges per sort block
#define NBLK 489    // ceil(2*NE / ET)
#define NBLKP 512   // padded row length of C/Rloc (bucket-major)

typedef __attribute__((ext_vector_type(8))) short short8v;   // 8 x bf16 (4 VGPR)
typedef __attribute__((ext_vector_type(4))) float f32x4;
typedef __attribute__((ext_vector_type(8))) unsigned short us8;
typedef __attribute__((ext_vector_type(2))) unsigned int uint2v;

struct Ptrs16 { const void* p[16]; };

struct GemmCfg {
  const unsigned short* Agg;   // may alias Hout (in-place) -> no __restrict
  const unsigned short* Xd;
  const unsigned short* Wp;
  const float* bias;
  unsigned short* Hout;
  float* stats;
};

__device__ __forceinline__ float bf2f(unsigned short u){
  unsigned int x = ((unsigned int)u) << 16;
  return __builtin_bit_cast(float, x);
}
__device__ __forceinline__ unsigned short f2bf(float f){
  unsigned int x = __builtin_bit_cast(unsigned int, f);
  unsigned int r = x + 0x7fffu + ((x >> 16) & 1u);   // RNE
  return (unsigned short)(r >> 16);
}

// ---- dtype sniff + small-param convert + stats zero (single block) ----
__global__ __launch_bounds__(256) void detect2_k(const unsigned short* emb,
                                                 const unsigned int* esrc,
                                                 int* flags, Ptrs16 ps,
                                                 float* params, float* stats){
  __shared__ int cnt0, cnt1, sf0;
  int t = threadIdx.x;
  if (t == 0){ cnt0 = 0; cnt1 = 0; }
  __syncthreads();
  int c0 = 0, c1 = 0;
  #pragma unroll
  for (int s = 0; s < 4; ++s){
    int i = (t*4 + s) * 14;
    float af = fabsf(bf2f(emb[i]));
    if (af > 0.0009765625f && af < 32.0f) c0++;
    int e = t*4 + s;
    if (esrc[2*e + 1] != 0u) c1++;
  }
  atomicAdd(&cnt0, c0); atomicAdd(&cnt1, c1);
  __syncthreads();
  if (t == 0){
    int f0 = (cnt0 > 512) ? 1 : 0;
    int f1 = (cnt1 < 512) ? 1 : 0;
    flags[0] = f0; flags[1] = f1; sf0 = f0;
  }
  __syncthreads();
  int f0 = sf0;
  const int aidx[12] = {1,3,5,7,8,9,10,11,12,13,14,15};
  const int aoff[12] = {12288,24640,36992,49344,49408,49472,49536,49600,49664,49728,49792,49856};
  for (int base = t; base < 768; base += 256){
    int a = base >> 6, j = base & 63;
    const void* p = ps.p[aidx[a]];
    params[aoff[a] + j] = f0 ? bf2f(((const unsigned short*)p)[j]) : ((const float*)p)[j];
  }
  for (int z = t; z < 512; z += 256) stats[z] = 0.0f;
}

// ---- fused: blocks [0,128) prepack the 4 weight mats into MFMA frag order;
//      blocks [128, 128+n8/256) canonicalize embeddings into union bf16 x1 ----
__global__ __launch_bounds__(256) void convpp_k(const void* uin, const void* iin,
                                                unsigned short* __restrict__ out,
                                                Ptrs16 ps, unsigned short* __restrict__ wpack,
                                                const int* flags, int n8){
  int bid = blockIdx.x;
  if (bid < 128){
    int i = bid*256 + threadIdx.x;
    int m = i >> 13, f = i & 8191;
    int r   = f & 7;
    int c16 = (f >> 3) & 15;
    int kg  = (f >> 7) & 3;
    int c   = (f >> 9) & 3;
    int t2  = (f >> 11) & 1;
    int s   = (f >> 12) & 1;
    int k = s*64 + t2*32 + kg*8 + r;
    int j = k*DIM + c*16 + c16;
    const void* wp = ps.p[m*2];        // W_go1, W_back1, W_go2, W_back2
    float v = flags[0] ? bf2f(((const unsigned short*)wp)[j]) : ((const float*)wp)[j];
    wpack[i] = f2bf(v);
    return;
  }
  int i = (bid - 128)*256 + threadIdx.x;
  if (i >= n8) return;
  int item = (i >= RN*8);
  const void* in = item ? iin : uin;
  int li = item ? i - RN*8 : i;
  us8 o;
  if (flags[0]){
    o = ((const us8*)in)[li];
  } else {
    const float* f = (const float*)in + (size_t)li*8;
    #pragma unroll
    for (int r = 0; r < 8; ++r) o[r] = f2bf(f[r]);
  }
  ((us8*)out)[i] = o;
}

// ==== CSR build: single-read merged histogram + scatter (validated R11) ====
__global__ __launch_bounds__(256) void pass12_k(const unsigned int* go_src, const unsigned int* go_dst,
                                                const unsigned int* back_src, const unsigned int* back_dst,
                                                int* __restrict__ C, int* __restrict__ Rloc,
                                                unsigned int* __restrict__ slab, const int* flags){
  __shared__ unsigned int spk[ET];      // 16KB: src | row_in_bucket<<18
  __shared__ unsigned short sbk[ET];    // 8KB: bucket id (0xFFFF = invalid)
  __shared__ int h[1024];               // histogram -> cursors
  __shared__ int ps[256];
  int blk = blockIdx.x, t = threadIdx.x;
  #pragma unroll
  for (int q = 0; q < 4; ++q) h[t + q*256] = 0;
  __syncthreads();
  int i64 = flags[1];
  int e0 = blk*ET;
  #pragma unroll
  for (int j = 0; j < 16; ++j){
    int e = e0 + j*256 + t;
    int li = j*256 + t;
    if (e < 2*NE){
      int rel = e >= NE;
      int ei = rel ? e - NE : e;
      const unsigned int* pd = rel ? back_dst : go_dst;
      const unsigned int* psr = rel ? back_src : go_src;
      int d  = i64 ? (int)pd[2*ei]  : (int)pd[ei];
      int sc = i64 ? (int)psr[2*ei] : (int)psr[ei];
      int b = (rel ? NB_PR : 0) + (d >> 9);
      spk[li] = (unsigned)sc | ((unsigned)(d & 511) << 18);
      sbk[li] = (unsigned short)b;
      atomicAdd(&h[b], 1);
    } else {
      sbk[li] = 0xFFFFu;
    }
  }
  __syncthreads();
  int c4[4], p4[4]; int s = 0;
  #pragma unroll
  for (int q = 0; q < 4; ++q){ c4[q] = h[t*4 + q]; p4[q] = s; s += c4[q]; }
  ps[t] = s;
  __syncthreads();
  for (int o = 1; o < 256; o <<= 1){
    int x = (t >= o) ? ps[t-o] : 0;
    __syncthreads();
    ps[t] += x;
    __syncthreads();
  }
  int base = (t > 0) ? ps[t-1] : 0;
  #pragma unroll
  for (int q = 0; q < 4; ++q){
    int b = t*4 + q;
    if (b < NBB){
      C[b*NBLKP + blk]    = c4[q];
      Rloc[b*NBLKP + blk] = base + p4[q];
    }
  }
  __syncthreads();                       // scan reads done; reuse h as cursors
  #pragma unroll
  for (int q = 0; q < 4; ++q){
    int b = t*4 + q;
    h[b] = base + p4[q];
  }
  __syncthreads();
  #pragma unroll
  for (int j = 0; j < 16; ++j){
    int li = j*256 + t;
    unsigned short b = sbk[li];
    if (b != 0xFFFFu){
      int pos = atomicAdd(&h[b], 1);
      slab[(size_t)blk*ET + pos] = spk[li];
    }
  }
}

__global__ __launch_bounds__(256) void sizes_k(const int* __restrict__ C, int* __restrict__ S){
  int w = blockIdx.x*4 + (threadIdx.x >> 6);
  int lane = threadIdx.x & 63;
  if (w >= NBB) return;
  int sum = 0;
  for (int k = lane; k < NBLK; k += 64) sum += C[w*NBLKP + k];
  #pragma unroll
  for (int o = 32; o > 0; o >>= 1) sum += __shfl_down(sum, o, 64);
  if (lane == 0) S[w] = sum;
}

__global__ __launch_bounds__(1024) void scanS_k(const int* __restrict__ S, int* __restrict__ s0,
                                                int* __restrict__ rs){
  __shared__ int sh[1024];
  int t = threadIdx.x;
  int v = (t < NBB) ? S[t] : 0;
  sh[t] = v;
  __syncthreads();
  for (int o = 1; o < 1024; o <<= 1){
    int x = (t >= o) ? sh[t-o] : 0;
    __syncthreads();
    sh[t] += x;
    __syncthreads();
  }
  if (t < NBB) s0[t] = sh[t] - v;
  if (t == NBB-1){ s0[NBB] = sh[t]; rs[NR2] = 2*NE; }
}

// ---- per-RUN iteration (no binary search; validated R12). Thread t owns run t.
// col written in UNION space (+RN for back-relation sources = items) ----
__global__ __launch_bounds__(512) void buildCSR3_k(const int* __restrict__ C,
                                                   const int* __restrict__ Rloc,
                                                   const int* __restrict__ s0g,
                                                   const unsigned int* __restrict__ slab,
                                                   int* __restrict__ rs, int* __restrict__ col){
  __shared__ int lcnt[512], lsc[512], lcur[512];
  int b = blockIdx.x, t = threadIdx.x;
  int cnt = 0, rst = 0;
  if (t < NBLK){ cnt = C[b*NBLKP + t]; rst = Rloc[b*NBLKP + t]; }
  lcnt[t] = 0;
  __syncthreads();
  const unsigned int* sl = slab + (size_t)t*ET + rst;   // only touched when cnt>0
  for (int k = 0; k < cnt; ++k){
    unsigned int q = sl[k];
    atomicAdd(&lcnt[q >> 18], 1);
  }
  __syncthreads();
  int rv = lcnt[t];
  lsc[t] = rv;
  __syncthreads();
  for (int o = 1; o < 512; o <<= 1){
    int x = (t >= o) ? lsc[t-o] : 0;
    __syncthreads();
    lsc[t] += x;
    __syncthreads();
  }
  int s0b = s0g[b];
  int d0 = (b < NB_PR) ? b*512 : RN + (b - NB_PR)*512;
  int relEnd = (b < NB_PR) ? RN : NR2;
  int rows = relEnd - d0; if (rows > 512) rows = 512;
  int srcoff = (b < NB_PR) ? 0 : RN;
  int start = lsc[t] - rv;
  lcur[t] = start;
  if (t < rows) rs[d0 + t] = s0b + start;
  __syncthreads();
  for (int k = 0; k < cnt; ++k){
    unsigned int q = sl[k];
    int p = atomicAdd(&lcur[q >> 18], 1);
    col[s0b + p] = (int)(q & 0x3FFFFu) + srcoff;
  }
}

// ---- SpMM: union rows, quarter-wave per dst row, dual output base.
// col via lane-parallel load + shfl; two-tier wave-uniform depth.
// CACHED agg store (R14): consumed by gemm next -> keep in L2/L3. ----
__global__ __launch_bounds__(256) void spmmU_k(const int* __restrict__ rs, const int* __restrict__ col,
                                               const unsigned short* __restrict__ Xg,
                                               unsigned short* outA, unsigned short* outB){
  int wv = (int)((blockIdx.x*256 + threadIdx.x) >> 6);
  int lane = threadIdx.x & 63;
  int hl = lane & 15;
  int qb = lane & 48;                  // quarter base lane
  int row = wv*4 + (lane >> 4);        // grid exact: NR2/16 blocks
  int b = rs[row], e = rs[row+1];      // uniform within quarter
  int deg = e - b;
  int dq0 = __shfl(deg, 0), dq1 = __shfl(deg, 16);
  int dq2 = __shfl(deg, 32), dq3 = __shfl(deg, 48);
  int md = max(max(dq0, dq1), max(dq2, dq3));   // wave-uniform trip bound
  float a0 = 0, a1 = 0, a2 = 0, a3 = 0;

  if (md <= 8){                         // wave-uniform fast path (avg md ~8.5)
    if (md > 0){
      int cv = col[b + ((hl < deg) ? hl : 0)];   // lane hl holds col[b+hl]
      uint2v v[8];
      #pragma unroll
      for (int j = 0; j < 8; ++j){
        int ix = __shfl(cv, qb + j, 64);
        ix = ((unsigned)ix < (unsigned)NR2) ? ix : 0;
        v[j] = *(const uint2v*)((const char*)Xg + (((size_t)(unsigned)ix) << 7) + (hl << 3));
      }
      #pragma unroll
      for (int j = 0; j < 8; ++j){
        if (j < deg){
          a0 += bf2f((unsigned short)(v[j].x & 0xFFFFu));
          a1 += bf2f((unsigned short)(v[j].x >> 16));
          a2 += bf2f((unsigned short)(v[j].y & 0xFFFFu));
          a3 += bf2f((unsigned short)(v[j].y >> 16));
        }
      }
    }
  } else {
    for (int i = 0; i < md; i += 16){
      int o = i + hl;
      int cv = col[b + ((o < deg) ? o : 0)];     // lane hl holds col[b+i+hl]
      uint2v v[16];
      #pragma unroll
      for (int j = 0; j < 16; ++j){
        int ix = __shfl(cv, qb + j, 64);
        ix = ((unsigned)ix < (unsigned)NR2) ? ix : 0;
        v[j] = *(const uint2v*)((const char*)Xg + (((size_t)(unsigned)ix) << 7) + (hl << 3));
      }
      #pragma unroll
      for (int j = 0; j < 16; ++j){
        if (i + j < deg){
          a0 += bf2f((unsigned short)(v[j].x & 0xFFFFu));
          a1 += bf2f((unsigned short)(v[j].x >> 16));
          a2 += bf2f((unsigned short)(v[j].y & 0xFFFFu));
          a3 += bf2f((unsigned short)(v[j].y >> 16));
        }
      }
    }
  }
  float nrm = deg > 0 ? rsqrtf((float)deg) : 1.0f;
  uint2v pv;
  pv.x = (unsigned)f2bf(a0*nrm) | ((unsigned)f2bf(a1*nrm) << 16);
  pv.y = (unsigned)f2bf(a2*nrm) | ((unsigned)f2bf(a3*nrm) << 16);
  unsigned short* ob = (row < RN) ? (outA + ((size_t)row << 6))
                                  : (outB + ((size_t)(row - RN) << 6));
  *((uint2v*)ob + hl) = pv;            // cached: gemm reads this next
}

// ---- merged GEMM: blocks [0,half) run cfg A, [half,2*half) run cfg B.
// H = Xd@W[0:64] + Agg@W[64:128] + b; prepacked B frags; fused BN stats.
// Agg may alias Hout (in-place back-relation): loads precede stores per tile.
// CACHED Hout stores (consumed by bnapply/spmm/bnout next). ----
__global__ __launch_bounds__(256) void gemm2m_k(GemmCfg cA, GemmCfg cB){
  __shared__ float ls[128];
  for (int t0 = threadIdx.x; t0 < 128; t0 += 256) ls[t0] = 0.0f;
  __syncthreads();
  int half = (int)(gridDim.x >> 1);
  bool sec = ((int)blockIdx.x >= half);
  const unsigned short* Agg = sec ? cB.Agg : cA.Agg;
  const unsigned short* Xd  = sec ? cB.Xd  : cA.Xd;
  const unsigned short* Wp  = sec ? cB.Wp  : cA.Wp;
  const float* bias         = sec ? cB.bias : cA.bias;
  unsigned short* Hout      = sec ? cB.Hout : cA.Hout;
  float* stats              = sec ? cB.stats : cA.stats;
  int lb = sec ? (int)blockIdx.x - half : (int)blockIdx.x;
  int lane = threadIdx.x & 63;
  int gw = lb*4 + (int)(threadIdx.x >> 6);
  int nw = half*4;
  int c16 = lane & 15, kg = lane >> 4;

  short8v Bf[2][2][4];
  #pragma unroll
  for (int s = 0; s < 2; ++s)
    #pragma unroll
    for (int t2 = 0; t2 < 2; ++t2)
      #pragma unroll
      for (int c = 0; c < 4; ++c)
        Bf[s][t2][c] = ((const short8v*)Wp)[(((s*2 + t2)*4 + c)*4 + kg)*16 + c16];
  float bc[4];
  #pragma unroll
  for (int c = 0; c < 4; ++c) bc[c] = bias[c*16 + c16];

  float ssum[4] = {0,0,0,0}, ssq[4] = {0,0,0,0};
  const int ntile = RN/16;
  for (int tile = gw; tile < ntile; tile += nw){
    int r0 = tile*16;
    int ar = r0 + c16;
    short8v A00 = ((const short8v*)Xd)[ar*8 + kg];
    short8v A01 = ((const short8v*)Xd)[ar*8 + 4 + kg];
    short8v A10 = ((const short8v*)Agg)[ar*8 + kg];
    short8v A11 = ((const short8v*)Agg)[ar*8 + 4 + kg];
    f32x4 acc4[4];
    #pragma unroll
    for (int c = 0; c < 4; ++c){ f32x4 z = {bc[c],bc[c],bc[c],bc[c]}; acc4[c] = z; }
    #pragma unroll
    for (int c = 0; c < 4; ++c){
      acc4[c] = __builtin_amdgcn_mfma_f32_16x16x32_bf16(A00, Bf[0][0][c], acc4[c], 0, 0, 0);
      acc4[c] = __builtin_amdgcn_mfma_f32_16x16x32_bf16(A01, Bf[0][1][c], acc4[c], 0, 0, 0);
      acc4[c] = __builtin_amdgcn_mfma_f32_16x16x32_bf16(A10, Bf[1][0][c], acc4[c], 0, 0, 0);
      acc4[c] = __builtin_amdgcn_mfma_f32_16x16x32_bf16(A11, Bf[1][1][c], acc4[c], 0, 0, 0);
    }
    int orow = r0 + kg*4;   // C layout: col = lane&15, row = (lane>>4)*4 + reg [m89]
    #pragma unroll
    for (int c = 0; c < 4; ++c)
      #pragma unroll
      for (int r = 0; r < 4; ++r){
        float v = acc4[c][r];
        ssum[c] += v; ssq[c] += v*v;
        Hout[(size_t)(orow + r)*DIM + c*16 + c16] = f2bf(v);
      }
  }
  #pragma unroll
  for (int c = 0; c < 4; ++c){
    atomicAdd(&ls[c*16 + c16], ssum[c]);
    atomicAdd(&ls[64 + c*16 + c16], ssq[c]);
  }
  __syncthreads();
  for (int t0 = threadIdx.x; t0 < 128; t0 += 256) atomicAdd(&stats[t0], ls[t0]);
}

// ---- BN finalize for both halves of a layer ----
__global__ __launch_bounds__(128) void bnfin2_k(const float* stats,
                                                const float* gI, const float* beI, float* acI,
                                                const float* gU, const float* beU, float* acU){
  int t = threadIdx.x, j = t & 63;
  const float* st = (t < 64) ? stats : stats + 128;
  float mu  = st[j]    * (1.0f/RN);
  float var = st[64+j] * (1.0f/RN) - mu*mu;
  float inv = rsqrtf(var + 1e-5f);
  if (t < 64){ float a = gI[j]*inv; acI[j] = a; acI[64+j] = beI[j] - mu*a; }
  else       { float a = gU[j]*inv; acU[j] = a; acU[64+j] = beU[j] - mu*a; }
}

// ---- BN + SiLU in-place over the union buffer (users half then items half) ----
__global__ __launch_bounds__(256) void bnapply2_k(unsigned short* H,
                                                  const float* __restrict__ acU,
                                                  const float* __restrict__ acI, int n8){
  int i = blockIdx.x*256 + threadIdx.x;
  if (i >= n8) return;
  const float* ac = (i < RN*8) ? acU : acI;
  us8 v = ((us8*)H)[i];
  int cb = (i*8) & 63;
  #pragma unroll
  for (int r = 0; r < 8; ++r){
    float x = bf2f(v[r]);
    float y = ac[cb+r]*x + ac[64+cb+r];
    float o = y / (1.0f + expf(-y));
    v[r] = f2bf(o);
  }
  ((us8*)H)[i] = v;
}

// ---- BN + SiLU to d_out; user rows from Hu, item rows from Hi ----
__global__ __launch_bounds__(256) void bnout2_k(const unsigned short* __restrict__ Hu,
                                                const unsigned short* __restrict__ Hi,
                                                const float* __restrict__ acU,
                                                const float* __restrict__ acI,
                                                void* out, const int* __restrict__ flags, int n8){
  int i = blockIdx.x*256 + threadIdx.x;
  if (i >= n8) return;
  int item = (i >= RN*8);
  const float* ac = item ? acI : acU;
  us8 v = item ? ((const us8*)Hi)[i - RN*8] : ((const us8*)Hu)[i];
  int cb = (i*8) & 63;
  float o[8];
  #pragma unroll
  for (int r = 0; r < 8; ++r){
    float x = bf2f(v[r]);
    float y = ac[cb+r]*x + ac[64+cb+r];
    o[r] = y / (1.0f + expf(-y));
  }
  if (flags[0]){
    unsigned short* ob = (unsigned short*)out + (size_t)i*8;
    us8 wv;
    #pragma unroll
    for (int r = 0; r < 8; ++r) wv[r] = f2bf(o[r]);
    __builtin_nontemporal_store(wv, (us8*)ob);
  } else {
    float* ob = (float*)out + (size_t)i*8;
    f32x4 w0 = {o[0],o[1],o[2],o[3]}, w1 = {o[4],o[5],o[6],o[7]};
    __builtin_nontemporal_store(w0, (f32x4*)ob);
    __builtin_nontemporal_store(w1, (f32x4*)ob + 1);
  }
}

extern "C" void kernel_launch(void* const* d_in, const int* in_sizes, int n_in,
                              void* d_out, int out_size, void* d_ws, size_t ws_size,
                              hipStream_t stream){
  (void)in_sizes; (void)n_in; (void)out_size;
  const void* user_emb = d_in[0];
  const void* item_emb = d_in[1];
  const void* go_src   = d_in[18];
  const void* go_dst   = d_in[19];
  const void* back_src = d_in[20];
  const void* back_dst = d_in[21];

  char* ws = (char*)d_ws;
  size_t off = 0;
  auto alloc = [&](size_t bytes) -> void* {
    void* p = ws + off;
    off += (bytes + 255) & ~((size_t)255);
    return p;
  };
  int*   flags  = (int*)  alloc(64);
  float* params = (float*)alloc((size_t)49920*4);
  unsigned short* wpack = (unsigned short*)alloc((size_t)4*8192*2);
  float* bnac   = (float*)alloc(512*4);
  float* stats  = (float*)alloc(512*4);
  int*   Cmat   = (int*)  alloc((size_t)NBB*NBLKP*4);
  int*   Rloc   = (int*)  alloc((size_t)NBB*NBLKP*4);
  int*   Sbuf   = (int*)  alloc(1024*4);
  int*   s0g    = (int*)  alloc(1024*4);
  int*   rs_all = (int*)  alloc((size_t)(NR2+1)*4);
  int*   col_all= (int*)  alloc(((size_t)2*NE + 64)*4);              // +64 pad: deg-0 tail reads
  unsigned short* x1   = (unsigned short*)alloc((size_t)NR2*DIM*2);  // embeddings -> layer-2 agg/out
  unsigned short* x2   = (unsigned short*)alloc((size_t)NR2*DIM*2);  // slab -> layer-1 out (silu'd)
  unsigned short* agg1 = (unsigned short*)alloc((size_t)RN*DIM*2);   // go agg -> layer-2 item out
  if (off > ws_size) return;  // visible as absmax == 5.8125

  unsigned int* slab = (unsigned int*)x2;   // 8MB alias; dead after buildCSR3

  unsigned short* x1u = x1;
  unsigned short* x1i = x1 + (size_t)RN*DIM;
  unsigned short* x2u = x2;
  unsigned short* x2i = x2 + (size_t)RN*DIM;

  const int G8A = (NR2*DIM/8)/256;          // 12500
  const int GSU = NR2/16;                   // 25000 blocks: union spmm, 4 rows/wave

  float* b_go1 = params + 12288;
  float* b_bk1 = params + 24640;
  float* b_go2 = params + 36992;
  float* b_bk2 = params + 49344;
  float* g1u = params + 49408; float* be1u = params + 49472;
  float* g1i = params + 49536; float* be1i = params + 49600;
  float* g2u = params + 49664; float* be2u = params + 49728;
  float* g2i = params + 49792; float* be2i = params + 49856;

  Ptrs16 ps;
  for (int i = 0; i < 16; ++i) ps.p[i] = d_in[2+i];

  detect2_k<<<1,256,0,stream>>>((const unsigned short*)user_emb, (const unsigned int*)go_src,
                                flags, ps, params, stats);
  convpp_k<<<G8A + 128,256,0,stream>>>(user_emb, item_emb, x1, ps, wpack, flags, NR2*DIM/8);

  // ---- CSR build ----
  pass12_k<<<NBLK,256,0,stream>>>((const unsigned int*)go_src, (const unsigned int*)go_dst,
                                  (const unsigned int*)back_src, (const unsigned int*)back_dst,
                                  Cmat, Rloc, slab, flags);
  sizes_k<<<(NBB+3)/4,256,0,stream>>>(Cmat, Sbuf);
  scanS_k<<<1,1024,0,stream>>>(Sbuf, s0g, rs_all);
  buildCSR3_k<<<NBB,512,0,stream>>>(Cmat, Rloc, s0g, slab, rs_all, col_all);

  // ---- layer 1: one union spmm (go rows -> agg1, back rows -> x2u scratch),
  //      one merged gemm (go: agg1+x1i -> x2i; back: x2u+x1u -> x2u in-place) ----
  spmmU_k<<<GSU,256,0,stream>>>(rs_all, col_all, x1, agg1, x2u);
  {
    GemmCfg go1{agg1, x1i, wpack + 0*8192, b_go1, x2i, stats + 0};
    GemmCfg bk1{x2u,  x1u, wpack + 1*8192, b_bk1, x2u, stats + 128};
    gemm2m_k<<<2048,256,0,stream>>>(go1, bk1);
  }
  bnfin2_k<<<1,128,0,stream>>>(stats + 0, g1i, be1i, bnac + 0, g1u, be1u, bnac + 128);
  bnapply2_k<<<G8A,256,0,stream>>>(x2, bnac + 128, bnac + 0, NR2*DIM/8);

  // ---- layer 2: union spmm from silu'd x2 -> agg2 = x1 (union),
  //      merged gemm (go: x1lo+x2i -> agg1; back: x1hi+x2u -> x1hi in-place) ----
  spmmU_k<<<GSU,256,0,stream>>>(rs_all, col_all, x2, x1u, x1i);
  {
    GemmCfg go2{x1u, x2i, wpack + 2*8192, b_go2, agg1, stats + 256};
    GemmCfg bk2{x1i, x2u, wpack + 3*8192, b_bk2, x1i,  stats + 384};
    gemm2m_k<<<2048,256,0,stream>>>(go2, bk2);
  }
  bnfin2_k<<<1,128,0,stream>>>(stats + 256, g2i, be2i, bnac + 256, g2u, be2u, bnac + 384);
  bnout2_k<<<G8A,256,0,stream>>>(x1i, agg1, bnac + 384, bnac + 256, d_out, flags, NR2*DIM/8);
}

// Round 15
// 338.963 us; speedup vs baseline: 1.1024x; 1.1024x over previous
//
#include <hip/hip_runtime.h>
#include <cstdint>
#include <cstddef>

#define RN 200000   // nodes per side (NU == NI)
#define NR2 400000  // both sides
#define DIM 64
#define NE 1000000  // edges per relation
#define NB_PR 391   // buckets per relation (512 rows each)
#define NBB 782     // total buckets (go: 0..390, back: 391..781)
#define ET 4096     // edges per sort block
#define NBLK 489    // ceil(2*NE / ET)
#define NBLKP 512   // padded row length of C/Rloc (bucket-major)

typedef __attribute__((ext_vector_type(8))) short short8v;   // 8 x bf16 (4 VGPR)
typedef __attribute__((ext_vector_type(4))) float f32x4;
typedef __attribute__((ext_vector_type(8))) unsigned short us8;
typedef __attribute__((ext_vector_type(2))) unsigned int uint2v;

struct Ptrs16 { const void* p[16]; };

struct GemmCfg {
  const unsigned short* Agg;   // may alias Hout (in-place) -> no __restrict
  const unsigned short* Xd;
  const unsigned short* Wp;
  const float* bias;
  unsigned short* Hout;
  float* stats;
};

__device__ __forceinline__ float bf2f(unsigned short u){
  unsigned int x = ((unsigned int)u) << 16;
  return __builtin_bit_cast(float, x);
}
__device__ __forceinline__ unsigned short f2bf(float f){
  unsigned int x = __builtin_bit_cast(unsigned int, f);
  unsigned int r = x + 0x7fffu + ((x >> 16) & 1u);   // RNE
  return (unsigned short)(r >> 16);
}

// ---- dtype sniff + small-param convert + stats zero (single block) ----
__global__ __launch_bounds__(256) void detect2_k(const unsigned short* emb,
                                                 const unsigned int* esrc,
                                                 int* flags, Ptrs16 ps,
                                                 float* params, float* stats){
  __shared__ int cnt0, cnt1, sf0;
  int t = threadIdx.x;
  if (t == 0){ cnt0 = 0; cnt1 = 0; }
  __syncthreads();
  int c0 = 0, c1 = 0;
  #pragma unroll
  for (int s = 0; s < 4; ++s){
    int i = (t*4 + s) * 14;
    float af = fabsf(bf2f(emb[i]));
    if (af > 0.0009765625f && af < 32.0f) c0++;
    int e = t*4 + s;
    if (esrc[2*e + 1] != 0u) c1++;
  }
  atomicAdd(&cnt0, c0); atomicAdd(&cnt1, c1);
  __syncthreads();
  if (t == 0){
    int f0 = (cnt0 > 512) ? 1 : 0;
    int f1 = (cnt1 < 512) ? 1 : 0;
    flags[0] = f0; flags[1] = f1; sf0 = f0;
  }
  __syncthreads();
  int f0 = sf0;
  const int aidx[12] = {1,3,5,7,8,9,10,11,12,13,14,15};
  const int aoff[12] = {12288,24640,36992,49344,49408,49472,49536,49600,49664,49728,49792,49856};
  for (int base = t; base < 768; base += 256){
    int a = base >> 6, j = base & 63;
    const void* p = ps.p[aidx[a]];
    params[aoff[a] + j] = f0 ? bf2f(((const unsigned short*)p)[j]) : ((const float*)p)[j];
  }
  for (int z = t; z < 512; z += 256) stats[z] = 0.0f;
}

// ---- fused: blocks [0,128) prepack the 4 weight mats into MFMA frag order;
//      blocks [128, 128+n8/256) canonicalize embeddings into union bf16 x1 ----
__global__ __launch_bounds__(256) void convpp_k(const void* uin, const void* iin,
                                                unsigned short* __restrict__ out,
                                                Ptrs16 ps, unsigned short* __restrict__ wpack,
                                                const int* flags, int n8){
  int bid = blockIdx.x;
  if (bid < 128){
    int i = bid*256 + threadIdx.x;
    int m = i >> 13, f = i & 8191;
    int r   = f & 7;
    int c16 = (f >> 3) & 15;
    int kg  = (f >> 7) & 3;
    int c   = (f >> 9) & 3;
    int t2  = (f >> 11) & 1;
    int s   = (f >> 12) & 1;
    int k = s*64 + t2*32 + kg*8 + r;
    int j = k*DIM + c*16 + c16;
    const void* wp = ps.p[m*2];        // W_go1, W_back1, W_go2, W_back2
    float v = flags[0] ? bf2f(((const unsigned short*)wp)[j]) : ((const float*)wp)[j];
    wpack[i] = f2bf(v);
    return;
  }
  int i = (bid - 128)*256 + threadIdx.x;
  if (i >= n8) return;
  int item = (i >= RN*8);
  const void* in = item ? iin : uin;
  int li = item ? i - RN*8 : i;
  us8 o;
  if (flags[0]){
    o = ((const us8*)in)[li];
  } else {
    const float* f = (const float*)in + (size_t)li*8;
    #pragma unroll
    for (int r = 0; r < 8; ++r) o[r] = f2bf(f[r]);
  }
  ((us8*)out)[i] = o;
}

// ==== CSR build: single-read merged histogram + scatter (validated R11) ====
__global__ __launch_bounds__(256) void pass12_k(const unsigned int* go_src, const unsigned int* go_dst,
                                                const unsigned int* back_src, const unsigned int* back_dst,
                                                int* __restrict__ C, int* __restrict__ Rloc,
                                                unsigned int* __restrict__ slab, const int* flags){
  __shared__ unsigned int spk[ET];      // 16KB: src | row_in_bucket<<18
  __shared__ unsigned short sbk[ET];    // 8KB: bucket id (0xFFFF = invalid)
  __shared__ int h[1024];               // histogram -> cursors
  __shared__ int ps[256];
  int blk = blockIdx.x, t = threadIdx.x;
  #pragma unroll
  for (int q = 0; q < 4; ++q) h[t + q*256] = 0;
  __syncthreads();
  int i64 = flags[1];
  int e0 = blk*ET;
  #pragma unroll
  for (int j = 0; j < 16; ++j){
    int e = e0 + j*256 + t;
    int li = j*256 + t;
    if (e < 2*NE){
      int rel = e >= NE;
      int ei = rel ? e - NE : e;
      const unsigned int* pd = rel ? back_dst : go_dst;
      const unsigned int* psr = rel ? back_src : go_src;
      int d  = i64 ? (int)pd[2*ei]  : (int)pd[ei];
      int sc = i64 ? (int)psr[2*ei] : (int)psr[ei];
      int b = (rel ? NB_PR : 0) + (d >> 9);
      spk[li] = (unsigned)sc | ((unsigned)(d & 511) << 18);
      sbk[li] = (unsigned short)b;
      atomicAdd(&h[b], 1);
    } else {
      sbk[li] = 0xFFFFu;
    }
  }
  __syncthreads();
  int c4[4], p4[4]; int s = 0;
  #pragma unroll
  for (int q = 0; q < 4; ++q){ c4[q] = h[t*4 + q]; p4[q] = s; s += c4[q]; }
  ps[t] = s;
  __syncthreads();
  for (int o = 1; o < 256; o <<= 1){
    int x = (t >= o) ? ps[t-o] : 0;
    __syncthreads();
    ps[t] += x;
    __syncthreads();
  }
  int base = (t > 0) ? ps[t-1] : 0;
  #pragma unroll
  for (int q = 0; q < 4; ++q){
    int b = t*4 + q;
    if (b < NBB){
      C[b*NBLKP + blk]    = c4[q];
      Rloc[b*NBLKP + blk] = base + p4[q];
    }
  }
  __syncthreads();                       // scan reads done; reuse h as cursors
  #pragma unroll
  for (int q = 0; q < 4; ++q){
    int b = t*4 + q;
    h[b] = base + p4[q];
  }
  __syncthreads();
  #pragma unroll
  for (int j = 0; j < 16; ++j){
    int li = j*256 + t;
    unsigned short b = sbk[li];
    if (b != 0xFFFFu){
      int pos = atomicAdd(&h[b], 1);
      slab[(size_t)blk*ET + pos] = spk[li];
    }
  }
}

__global__ __launch_bounds__(256) void sizes_k(const int* __restrict__ C, int* __restrict__ S){
  int w = blockIdx.x*4 + (threadIdx.x >> 6);
  int lane = threadIdx.x & 63;
  if (w >= NBB) return;
  int sum = 0;
  for (int k = lane; k < NBLK; k += 64) sum += C[w*NBLKP + k];
  #pragma unroll
  for (int o = 32; o > 0; o >>= 1) sum += __shfl_down(sum, o, 64);
  if (lane == 0) S[w] = sum;
}

__global__ __launch_bounds__(1024) void scanS_k(const int* __restrict__ S, int* __restrict__ s0,
                                                int* __restrict__ rs){
  __shared__ int sh[1024];
  int t = threadIdx.x;
  int v = (t < NBB) ? S[t] : 0;
  sh[t] = v;
  __syncthreads();
  for (int o = 1; o < 1024; o <<= 1){
    int x = (t >= o) ? sh[t-o] : 0;
    __syncthreads();
    sh[t] += x;
    __syncthreads();
  }
  if (t < NBB) s0[t] = sh[t] - v;
  if (t == NBB-1){ s0[NBB] = sh[t]; rs[NR2] = 2*NE; }
}

// ---- per-RUN iteration (no binary search; validated R12). Thread t owns run t.
// col written in UNION space (+RN for back-relation sources = items) ----
__global__ __launch_bounds__(512) void buildCSR3_k(const int* __restrict__ C,
                                                   const int* __restrict__ Rloc,
                                                   const int* __restrict__ s0g,
                                                   const unsigned int* __restrict__ slab,
                                                   int* __restrict__ rs, int* __restrict__ col){
  __shared__ int lcnt[512], lsc[512], lcur[512];
  int b = blockIdx.x, t = threadIdx.x;
  int cnt = 0, rst = 0;
  if (t < NBLK){ cnt = C[b*NBLKP + t]; rst = Rloc[b*NBLKP + t]; }
  lcnt[t] = 0;
  __syncthreads();
  const unsigned int* sl = slab + (size_t)t*ET + rst;   // only touched when cnt>0
  for (int k = 0; k < cnt; ++k){
    unsigned int q = sl[k];
    atomicAdd(&lcnt[q >> 18], 1);
  }
  __syncthreads();
  int rv = lcnt[t];
  lsc[t] = rv;
  __syncthreads();
  for (int o = 1; o < 512; o <<= 1){
    int x = (t >= o) ? lsc[t-o] : 0;
    __syncthreads();
    lsc[t] += x;
    __syncthreads();
  }
  int s0b = s0g[b];
  int d0 = (b < NB_PR) ? b*512 : RN + (b - NB_PR)*512;
  int relEnd = (b < NB_PR) ? RN : NR2;
  int rows = relEnd - d0; if (rows > 512) rows = 512;
  int srcoff = (b < NB_PR) ? 0 : RN;
  int start = lsc[t] - rv;
  lcur[t] = start;
  if (t < rows) rs[d0 + t] = s0b + start;
  __syncthreads();
  for (int k = 0; k < cnt; ++k){
    unsigned int q = sl[k];
    int p = atomicAdd(&lcur[q >> 18], 1);
    col[s0b + p] = (int)(q & 0x3FFFFu) + srcoff;
  }
}

// ---- SpMM: union rows, quarter-wave per dst row, dual output base.
// col via lane-parallel load + shfl; two-tier wave-uniform depth. (R13-validated) ----
__global__ __launch_bounds__(256) void spmmU_k(const int* __restrict__ rs, const int* __restrict__ col,
                                               const unsigned short* __restrict__ Xg,
                                               unsigned short* outA, unsigned short* outB){
  int wv = (int)((blockIdx.x*256 + threadIdx.x) >> 6);
  int lane = threadIdx.x & 63;
  int hl = lane & 15;
  int qb = lane & 48;                  // quarter base lane
  int row = wv*4 + (lane >> 4);        // grid exact: NR2/16 blocks
  int b = rs[row], e = rs[row+1];      // uniform within quarter
  int deg = e - b;
  int dq0 = __shfl(deg, 0), dq1 = __shfl(deg, 16);
  int dq2 = __shfl(deg, 32), dq3 = __shfl(deg, 48);
  int md = max(max(dq0, dq1), max(dq2, dq3));   // wave-uniform trip bound
  float a0 = 0, a1 = 0, a2 = 0, a3 = 0;

  if (md <= 8){                         // wave-uniform fast path (avg md ~8.5)
    if (md > 0){
      int cv = col[b + ((hl < deg) ? hl : 0)];   // lane hl holds col[b+hl]
      uint2v v[8];
      #pragma unroll
      for (int j = 0; j < 8; ++j){
        int ix = __shfl(cv, qb + j, 64);
        ix = ((unsigned)ix < (unsigned)NR2) ? ix : 0;
        v[j] = *(const uint2v*)((const char*)Xg + (((size_t)(unsigned)ix) << 7) + (hl << 3));
      }
      #pragma unroll
      for (int j = 0; j < 8; ++j){
        if (j < deg){
          a0 += bf2f((unsigned short)(v[j].x & 0xFFFFu));
          a1 += bf2f((unsigned short)(v[j].x >> 16));
          a2 += bf2f((unsigned short)(v[j].y & 0xFFFFu));
          a3 += bf2f((unsigned short)(v[j].y >> 16));
        }
      }
    }
  } else {
    for (int i = 0; i < md; i += 16){
      int o = i + hl;
      int cv = col[b + ((o < deg) ? o : 0)];     // lane hl holds col[b+i+hl]
      uint2v v[16];
      #pragma unroll
      for (int j = 0; j < 16; ++j){
        int ix = __shfl(cv, qb + j, 64);
        ix = ((unsigned)ix < (unsigned)NR2) ? ix : 0;
        v[j] = *(const uint2v*)((const char*)Xg + (((size_t)(unsigned)ix) << 7) + (hl << 3));
      }
      #pragma unroll
      for (int j = 0; j < 16; ++j){
        if (i + j < deg){
          a0 += bf2f((unsigned short)(v[j].x & 0xFFFFu));
          a1 += bf2f((unsigned short)(v[j].x >> 16));
          a2 += bf2f((unsigned short)(v[j].y & 0xFFFFu));
          a3 += bf2f((unsigned short)(v[j].y >> 16));
        }
      }
    }
  }
  float nrm = deg > 0 ? rsqrtf((float)deg) : 1.0f;
  uint2v pv;
  pv.x = (unsigned)f2bf(a0*nrm) | ((unsigned)f2bf(a1*nrm) << 16);
  pv.y = (unsigned)f2bf(a2*nrm) | ((unsigned)f2bf(a3*nrm) << 16);
  unsigned short* ob = (row < RN) ? (outA + ((size_t)row << 6))
                                  : (outB + ((size_t)(row - RN) << 6));
  __builtin_nontemporal_store(pv, (uint2v*)ob + hl);
}

// ---- merged GEMM R15: 2 tiles/iteration + explicit next-pair prefetch.
// 16 independent 16B loads in flight per wave -> hides HBM latency that made
// R13/R14's version latency-bound (1690 cy/tile vs ~150 cy issue work).
// Agg may alias Hout: each wave reads ONLY its own tiles' rows (incl.
// prefetch) and writes only its own rows -> no cross-wave hazard. ----
__global__ __launch_bounds__(256) void gemm2m_k(GemmCfg cA, GemmCfg cB){
  __shared__ float ls[128];
  for (int t0 = threadIdx.x; t0 < 128; t0 += 256) ls[t0] = 0.0f;
  __syncthreads();
  int half = (int)(gridDim.x >> 1);
  bool sec = ((int)blockIdx.x >= half);
  const unsigned short* Agg = sec ? cB.Agg : cA.Agg;
  const unsigned short* Xd  = sec ? cB.Xd  : cA.Xd;
  const unsigned short* Wp  = sec ? cB.Wp  : cA.Wp;
  const float* bias         = sec ? cB.bias : cA.bias;
  unsigned short* Hout      = sec ? cB.Hout : cA.Hout;
  float* stats              = sec ? cB.stats : cA.stats;
  int lb = sec ? (int)blockIdx.x - half : (int)blockIdx.x;
  int lane = threadIdx.x & 63;
  int gw = lb*4 + (int)(threadIdx.x >> 6);
  int nw = half*4;
  int c16 = lane & 15, kg = lane >> 4;

  short8v Bf[2][2][4];
  #pragma unroll
  for (int s = 0; s < 2; ++s)
    #pragma unroll
    for (int t2 = 0; t2 < 2; ++t2)
      #pragma unroll
      for (int c = 0; c < 4; ++c)
        Bf[s][t2][c] = ((const short8v*)Wp)[(((s*2 + t2)*4 + c)*4 + kg)*16 + c16];
  float bc[4];
  #pragma unroll
  for (int c = 0; c < 4; ++c) bc[c] = bias[c*16 + c16];

  const short8v* xd = (const short8v*)Xd;
  const short8v* ag = (const short8v*)Agg;
  const int npair = RN/32;             // 6250 pairs of 16-row tiles
  float ssum[4] = {0,0,0,0}, ssq[4] = {0,0,0,0};

  short8v cur[8], nxt[8];
  int tp = gw;
  if (tp < npair){
    size_t ra = (size_t)(tp*32 + c16);          // tile a rows
    size_t rb = ra + 16;                         // tile b rows
    cur[0] = xd[ra*8 + kg];     cur[1] = xd[ra*8 + 4 + kg];
    cur[2] = ag[ra*8 + kg];     cur[3] = ag[ra*8 + 4 + kg];
    cur[4] = xd[rb*8 + kg];     cur[5] = xd[rb*8 + 4 + kg];
    cur[6] = ag[rb*8 + kg];     cur[7] = ag[rb*8 + 4 + kg];
  }
  for (; tp < npair; ){
    int tn = tp + nw;
    if (tn < npair){                             // prefetch next pair (8 loads)
      size_t ra = (size_t)(tn*32 + c16);
      size_t rb = ra + 16;
      nxt[0] = xd[ra*8 + kg];   nxt[1] = xd[ra*8 + 4 + kg];
      nxt[2] = ag[ra*8 + kg];   nxt[3] = ag[ra*8 + 4 + kg];
      nxt[4] = xd[rb*8 + kg];   nxt[5] = xd[rb*8 + 4 + kg];
      nxt[6] = ag[rb*8 + kg];   nxt[7] = ag[rb*8 + 4 + kg];
    }
    #pragma unroll
    for (int h = 0; h < 2; ++h){                 // tile a (h=0), tile b (h=1)
      f32x4 acc4[4];
      #pragma unroll
      for (int c = 0; c < 4; ++c){ f32x4 z = {bc[c],bc[c],bc[c],bc[c]}; acc4[c] = z; }
      #pragma unroll
      for (int c = 0; c < 4; ++c){
        acc4[c] = __builtin_amdgcn_mfma_f32_16x16x32_bf16(cur[h*4+0], Bf[0][0][c], acc4[c], 0, 0, 0);
        acc4[c] = __builtin_amdgcn_mfma_f32_16x16x32_bf16(cur[h*4+1], Bf[0][1][c], acc4[c], 0, 0, 0);
        acc4[c] = __builtin_amdgcn_mfma_f32_16x16x32_bf16(cur[h*4+2], Bf[1][0][c], acc4[c], 0, 0, 0);
        acc4[c] = __builtin_amdgcn_mfma_f32_16x16x32_bf16(cur[h*4+3], Bf[1][1][c], acc4[c], 0, 0, 0);
      }
      int orow = tp*32 + h*16 + kg*4;   // C layout: col = lane&15, row = (lane>>4)*4 + reg [m89]
      #pragma unroll
      for (int c = 0; c < 4; ++c)
        #pragma unroll
        for (int r = 0; r < 4; ++r){
          float v = acc4[c][r];
          ssum[c] += v; ssq[c] += v*v;
          __builtin_nontemporal_store(f2bf(v), &Hout[(size_t)(orow + r)*DIM + c*16 + c16]);
        }
    }
    #pragma unroll
    for (int q = 0; q < 8; ++q) cur[q] = nxt[q];
    tp = tn;
  }
  #pragma unroll
  for (int c = 0; c < 4; ++c){
    atomicAdd(&ls[c*16 + c16], ssum[c]);
    atomicAdd(&ls[64 + c*16 + c16], ssq[c]);
  }
  __syncthreads();
  for (int t0 = threadIdx.x; t0 < 128; t0 += 256) atomicAdd(&stats[t0], ls[t0]);
}

// ---- BN finalize for both halves of a layer ----
__global__ __launch_bounds__(128) void bnfin2_k(const float* stats,
                                                const float* gI, const float* beI, float* acI,
                                                const float* gU, const float* beU, float* acU){
  int t = threadIdx.x, j = t & 63;
  const float* st = (t < 64) ? stats : stats + 128;
  float mu  = st[j]    * (1.0f/RN);
  float var = st[64+j] * (1.0f/RN) - mu*mu;
  float inv = rsqrtf(var + 1e-5f);
  if (t < 64){ float a = gI[j]*inv; acI[j] = a; acI[64+j] = beI[j] - mu*a; }
  else       { float a = gU[j]*inv; acU[j] = a; acU[64+j] = beU[j] - mu*a; }
}

// ---- BN + SiLU in-place over the union buffer (users half then items half) ----
__global__ __launch_bounds__(256) void bnapply2_k(unsigned short* H,
                                                  const float* __restrict__ acU,
                                                  const float* __restrict__ acI, int n8){
  int i = blockIdx.x*256 + threadIdx.x;
  if (i >= n8) return;
  const float* ac = (i < RN*8) ? acU : acI;
  us8 v = ((us8*)H)[i];
  int cb = (i*8) & 63;
  #pragma unroll
  for (int r = 0; r < 8; ++r){
    float x = bf2f(v[r]);
    float y = ac[cb+r]*x + ac[64+cb+r];
    float o = y / (1.0f + expf(-y));
    v[r] = f2bf(o);
  }
  ((us8*)H)[i] = v;
}

// ---- BN + SiLU to d_out; user rows from Hu, item rows from Hi ----
__global__ __launch_bounds__(256) void bnout2_k(const unsigned short* __restrict__ Hu,
                                                const unsigned short* __restrict__ Hi,
                                                const float* __restrict__ acU,
                                                const float* __restrict__ acI,
                                                void* out, const int* __restrict__ flags, int n8){
  int i = blockIdx.x*256 + threadIdx.x;
  if (i >= n8) return;
  int item = (i >= RN*8);
  const float* ac = item ? acI : acU;
  us8 v = item ? ((const us8*)Hi)[i - RN*8] : ((const us8*)Hu)[i];
  int cb = (i*8) & 63;
  float o[8];
  #pragma unroll
  for (int r = 0; r < 8; ++r){
    float x = bf2f(v[r]);
    float y = ac[cb+r]*x + ac[64+cb+r];
    o[r] = y / (1.0f + expf(-y));
  }
  if (flags[0]){
    unsigned short* ob = (unsigned short*)out + (size_t)i*8;
    us8 wv;
    #pragma unroll
    for (int r = 0; r < 8; ++r) wv[r] = f2bf(o[r]);
    __builtin_nontemporal_store(wv, (us8*)ob);
  } else {
    float* ob = (float*)out + (size_t)i*8;
    f32x4 w0 = {o[0],o[1],o[2],o[3]}, w1 = {o[4],o[5],o[6],o[7]};
    __builtin_nontemporal_store(w0, (f32x4*)ob);
    __builtin_nontemporal_store(w1, (f32x4*)ob + 1);
  }
}

extern "C" void kernel_launch(void* const* d_in, const int* in_sizes, int n_in,
                              void* d_out, int out_size, void* d_ws, size_t ws_size,
                              hipStream_t stream){
  (void)in_sizes; (void)n_in; (void)out_size;
  const void* user_emb = d_in[0];
  const void* item_emb = d_in[1];
  const void* go_src   = d_in[18];
  const void* go_dst   = d_in[19];
  const void* back_src = d_in[20];
  const void* back_dst = d_in[21];

  char* ws = (char*)d_ws;
  size_t off = 0;
  auto alloc = [&](size_t bytes) -> void* {
    void* p = ws + off;
    off += (bytes + 255) & ~((size_t)255);
    return p;
  };
  int*   flags  = (int*)  alloc(64);
  float* params = (float*)alloc((size_t)49920*4);
  unsigned short* wpack = (unsigned short*)alloc((size_t)4*8192*2);
  float* bnac   = (float*)alloc(512*4);
  float* stats  = (float*)alloc(512*4);
  int*   Cmat   = (int*)  alloc((size_t)NBB*NBLKP*4);
  int*   Rloc   = (int*)  alloc((size_t)NBB*NBLKP*4);
  int*   Sbuf   = (int*)  alloc(1024*4);
  int*   s0g    = (int*)  alloc(1024*4);
  int*   rs_all = (int*)  alloc((size_t)(NR2+1)*4);
  int*   col_all= (int*)  alloc(((size_t)2*NE + 64)*4);              // +64 pad: deg-0 tail reads
  unsigned short* x1   = (unsigned short*)alloc((size_t)NR2*DIM*2);  // embeddings -> layer-2 agg/out
  unsigned short* x2   = (unsigned short*)alloc((size_t)NR2*DIM*2);  // slab -> layer-1 out (silu'd)
  unsigned short* agg1 = (unsigned short*)alloc((size_t)RN*DIM*2);   // go agg -> layer-2 item out
  if (off > ws_size) return;  // visible as absmax == 5.8125

  unsigned int* slab = (unsigned int*)x2;   // 8MB alias; dead after buildCSR3

  unsigned short* x1u = x1;
  unsigned short* x1i = x1 + (size_t)RN*DIM;
  unsigned short* x2u = x2;
  unsigned short* x2i = x2 + (size_t)RN*DIM;

  const int G8A = (NR2*DIM/8)/256;          // 12500
  const int GSU = NR2/16;                   // 25000 blocks: union spmm, 4 rows/wave

  float* b_go1 = params + 12288;
  float* b_bk1 = params + 24640;
  float* b_go2 = params + 36992;
  float* b_bk2 = params + 49344;
  float* g1u = params + 49408; float* be1u = params + 49472;
  float* g1i = params + 49536; float* be1i = params + 49600;
  float* g2u = params + 49664; float* be2u = params + 49728;
  float* g2i = params + 49792; float* be2i = params + 49856;

  Ptrs16 ps;
  for (int i = 0; i < 16; ++i) ps.p[i] = d_in[2+i];

  detect2_k<<<1,256,0,stream>>>((const unsigned short*)user_emb, (const unsigned int*)go_src,
                                flags, ps, params, stats);
  convpp_k<<<G8A + 128,256,0,stream>>>(user_emb, item_emb, x1, ps, wpack, flags, NR2*DIM/8);

  // ---- CSR build ----
  pass12_k<<<NBLK,256,0,stream>>>((const unsigned int*)go_src, (const unsigned int*)go_dst,
                                  (const unsigned int*)back_src, (const unsigned int*)back_dst,
                                  Cmat, Rloc, slab, flags);
  sizes_k<<<(NBB+3)/4,256,0,stream>>>(Cmat, Sbuf);
  scanS_k<<<1,1024,0,stream>>>(Sbuf, s0g, rs_all);
  buildCSR3_k<<<NBB,512,0,stream>>>(Cmat, Rloc, s0g, slab, rs_all, col_all);

  // ---- layer 1: one union spmm (go rows -> agg1, back rows -> x2u scratch),
  //      one merged gemm (go: agg1+x1i -> x2i; back: x2u+x1u -> x2u in-place) ----
  spmmU_k<<<GSU,256,0,stream>>>(rs_all, col_all, x1, agg1, x2u);
  {
    GemmCfg go1{agg1, x1i, wpack + 0*8192, b_go1, x2i, stats + 0};
    GemmCfg bk1{x2u,  x1u, wpack + 1*8192, b_bk1, x2u, stats + 128};
    gemm2m_k<<<1024,256,0,stream>>>(go1, bk1);
  }
  bnfin2_k<<<1,128,0,stream>>>(stats + 0, g1i, be1i, bnac + 0, g1u, be1u, bnac + 128);
  bnapply2_k<<<G8A,256,0,stream>>>(x2, bnac + 128, bnac + 0, NR2*DIM/8);

  // ---- layer 2: union spmm from silu'd x2 -> agg2 = x1 (union),
  //      merged gemm (go: x1lo+x2i -> agg1; back: x1hi+x2u -> x1hi in-place) ----
  spmmU_k<<<GSU,256,0,stream>>>(rs_all, col_all, x2, x1u, x1i);
  {
    GemmCfg go2{x1u, x2i, wpack + 2*8192, b_go2, agg1, stats + 256};
    GemmCfg bk2{x1i, x2u, wpack + 3*8192, b_bk2, x1i,  stats + 384};
    gemm2m_k<<<1024,256,0,stream>>>(go2, bk2);
  }
  bnfin2_k<<<1,128,0,stream>>>(stats + 256, g2i, be2i, bnac + 256, g2u, be2u, bnac + 384);
  bnout2_k<<<G8A,256,0,stream>>>(x1i, agg1, bnac + 384, bnac + 256, d_out, flags, NR2*DIM/8);
}

// Round 16
// 330.823 us; speedup vs baseline: 1.1295x; 1.0246x over previous
//
#include <hip/hip_runtime.h>
#include <cstdint>
#include <cstddef>

#define RN 200000   // nodes per side (NU == NI)
#define NR2 400000  // both sides
#define DIM 64
#define NE 1000000  // edges per relation
#define NB_PR 391   // buckets per relation (512 rows each)
#define NBB 782     // total buckets (go: 0..390, back: 391..781)
#define ET 4096     // edges per sort block
#define NBLK 489    // ceil(2*NE / ET)
#define NBLKP 512   // padded row length of C/Rloc (bucket-major)

typedef __attribute__((ext_vector_type(8))) short short8v;   // 8 x bf16 (4 VGPR)
typedef __attribute__((ext_vector_type(4))) float f32x4;
typedef __attribute__((ext_vector_type(8))) unsigned short us8;
typedef __attribute__((ext_vector_type(2))) unsigned int uint2v;

struct Ptrs16 { const void* p[16]; };

struct GemmCfg {
  const unsigned short* Agg;   // may alias Hout (in-place) -> no __restrict
  const unsigned short* Xd;
  const unsigned short* Wp;
  const float* bias;
  unsigned short* Hout;
  float* stats;
};

__device__ __forceinline__ float bf2f(unsigned short u){
  unsigned int x = ((unsigned int)u) << 16;
  return __builtin_bit_cast(float, x);
}
__device__ __forceinline__ unsigned short f2bf(float f){
  unsigned int x = __builtin_bit_cast(unsigned int, f);
  unsigned int r = x + 0x7fffu + ((x >> 16) & 1u);   // RNE
  return (unsigned short)(r >> 16);
}

// ---- dtype sniff + small-param convert + stats zero (single block) ----
__global__ __launch_bounds__(256) void detect2_k(const unsigned short* emb,
                                                 const unsigned int* esrc,
                                                 int* flags, Ptrs16 ps,
                                                 float* params, float* stats){
  __shared__ int cnt0, cnt1, sf0;
  int t = threadIdx.x;
  if (t == 0){ cnt0 = 0; cnt1 = 0; }
  __syncthreads();
  int c0 = 0, c1 = 0;
  #pragma unroll
  for (int s = 0; s < 4; ++s){
    int i = (t*4 + s) * 14;
    float af = fabsf(bf2f(emb[i]));
    if (af > 0.0009765625f && af < 32.0f) c0++;
    int e = t*4 + s;
    if (esrc[2*e + 1] != 0u) c1++;
  }
  atomicAdd(&cnt0, c0); atomicAdd(&cnt1, c1);
  __syncthreads();
  if (t == 0){
    int f0 = (cnt0 > 512) ? 1 : 0;
    int f1 = (cnt1 < 512) ? 1 : 0;
    flags[0] = f0; flags[1] = f1; sf0 = f0;
  }
  __syncthreads();
  int f0 = sf0;
  const int aidx[12] = {1,3,5,7,8,9,10,11,12,13,14,15};
  const int aoff[12] = {12288,24640,36992,49344,49408,49472,49536,49600,49664,49728,49792,49856};
  for (int base = t; base < 768; base += 256){
    int a = base >> 6, j = base & 63;
    const void* p = ps.p[aidx[a]];
    params[aoff[a] + j] = f0 ? bf2f(((const unsigned short*)p)[j]) : ((const float*)p)[j];
  }
  for (int z = t; z < 512; z += 256) stats[z] = 0.0f;
}

// ---- fused: blocks [0,128) prepack the 4 weight mats into MFMA frag order;
//      blocks [128, 128+n8/256) canonicalize embeddings into union bf16 x1 ----
__global__ __launch_bounds__(256) void convpp_k(const void* uin, const void* iin,
                                                unsigned short* __restrict__ out,
                                                Ptrs16 ps, unsigned short* __restrict__ wpack,
                                                const int* flags, int n8){
  int bid = blockIdx.x;
  if (bid < 128){
    int i = bid*256 + threadIdx.x;
    int m = i >> 13, f = i & 8191;
    int r   = f & 7;
    int c16 = (f >> 3) & 15;
    int kg  = (f >> 7) & 3;
    int c   = (f >> 9) & 3;
    int t2  = (f >> 11) & 1;
    int s   = (f >> 12) & 1;
    int k = s*64 + t2*32 + kg*8 + r;
    int j = k*DIM + c*16 + c16;
    const void* wp = ps.p[m*2];        // W_go1, W_back1, W_go2, W_back2
    float v = flags[0] ? bf2f(((const unsigned short*)wp)[j]) : ((const float*)wp)[j];
    wpack[i] = f2bf(v);
    return;
  }
  int i = (bid - 128)*256 + threadIdx.x;
  if (i >= n8) return;
  int item = (i >= RN*8);
  const void* in = item ? iin : uin;
  int li = item ? i - RN*8 : i;
  us8 o;
  if (flags[0]){
    o = ((const us8*)in)[li];
  } else {
    const float* f = (const float*)in + (size_t)li*8;
    #pragma unroll
    for (int r = 0; r < 8; ++r) o[r] = f2bf(f[r]);
  }
  ((us8*)out)[i] = o;
}

// ==== CSR build: single-read merged histogram + scatter (validated R11) ====
__global__ __launch_bounds__(256) void pass12_k(const unsigned int* go_src, const unsigned int* go_dst,
                                                const unsigned int* back_src, const unsigned int* back_dst,
                                                int* __restrict__ C, int* __restrict__ Rloc,
                                                unsigned int* __restrict__ slab, const int* flags){
  __shared__ unsigned int spk[ET];      // 16KB: src | row_in_bucket<<18
  __shared__ unsigned short sbk[ET];    // 8KB: bucket id (0xFFFF = invalid)
  __shared__ int h[1024];               // histogram -> cursors
  __shared__ int ps[256];
  int blk = blockIdx.x, t = threadIdx.x;
  #pragma unroll
  for (int q = 0; q < 4; ++q) h[t + q*256] = 0;
  __syncthreads();
  int i64 = flags[1];
  int e0 = blk*ET;
  #pragma unroll
  for (int j = 0; j < 16; ++j){
    int e = e0 + j*256 + t;
    int li = j*256 + t;
    if (e < 2*NE){
      int rel = e >= NE;
      int ei = rel ? e - NE : e;
      const unsigned int* pd = rel ? back_dst : go_dst;
      const unsigned int* psr = rel ? back_src : go_src;
      int d  = i64 ? (int)pd[2*ei]  : (int)pd[ei];
      int sc = i64 ? (int)psr[2*ei] : (int)psr[ei];
      int b = (rel ? NB_PR : 0) + (d >> 9);
      spk[li] = (unsigned)sc | ((unsigned)(d & 511) << 18);
      sbk[li] = (unsigned short)b;
      atomicAdd(&h[b], 1);
    } else {
      sbk[li] = 0xFFFFu;
    }
  }
  __syncthreads();
  int c4[4], p4[4]; int s = 0;
  #pragma unroll
  for (int q = 0; q < 4; ++q){ c4[q] = h[t*4 + q]; p4[q] = s; s += c4[q]; }
  ps[t] = s;
  __syncthreads();
  for (int o = 1; o < 256; o <<= 1){
    int x = (t >= o) ? ps[t-o] : 0;
    __syncthreads();
    ps[t] += x;
    __syncthreads();
  }
  int base = (t > 0) ? ps[t-1] : 0;
  #pragma unroll
  for (int q = 0; q < 4; ++q){
    int b = t*4 + q;
    if (b < NBB){
      C[b*NBLKP + blk]    = c4[q];
      Rloc[b*NBLKP + blk] = base + p4[q];
    }
  }
  __syncthreads();                       // scan reads done; reuse h as cursors
  #pragma unroll
  for (int q = 0; q < 4; ++q){
    int b = t*4 + q;
    h[b] = base + p4[q];
  }
  __syncthreads();
  #pragma unroll
  for (int j = 0; j < 16; ++j){
    int li = j*256 + t;
    unsigned short b = sbk[li];
    if (b != 0xFFFFu){
      int pos = atomicAdd(&h[b], 1);
      slab[(size_t)blk*ET + pos] = spk[li];
    }
  }
}

__global__ __launch_bounds__(256) void sizes_k(const int* __restrict__ C, int* __restrict__ S){
  int w = blockIdx.x*4 + (threadIdx.x >> 6);
  int lane = threadIdx.x & 63;
  if (w >= NBB) return;
  int sum = 0;
  for (int k = lane; k < NBLK; k += 64) sum += C[w*NBLKP + k];
  #pragma unroll
  for (int o = 32; o > 0; o >>= 1) sum += __shfl_down(sum, o, 64);
  if (lane == 0) S[w] = sum;
}

__global__ __launch_bounds__(1024) void scanS_k(const int* __restrict__ S, int* __restrict__ s0,
                                                int* __restrict__ rs){
  __shared__ int sh[1024];
  int t = threadIdx.x;
  int v = (t < NBB) ? S[t] : 0;
  sh[t] = v;
  __syncthreads();
  for (int o = 1; o < 1024; o <<= 1){
    int x = (t >= o) ? sh[t-o] : 0;
    __syncthreads();
    sh[t] += x;
    __syncthreads();
  }
  if (t < NBB) s0[t] = sh[t] - v;
  if (t == NBB-1){ s0[NBB] = sh[t]; rs[NR2] = 2*NE; }
}

// ---- per-RUN iteration (no binary search; validated R12). Thread t owns run t.
// col written in UNION space (+RN for back-relation sources = items) ----
__global__ __launch_bounds__(512) void buildCSR3_k(const int* __restrict__ C,
                                                   const int* __restrict__ Rloc,
                                                   const int* __restrict__ s0g,
                                                   const unsigned int* __restrict__ slab,
                                                   int* __restrict__ rs, int* __restrict__ col){
  __shared__ int lcnt[512], lsc[512], lcur[512];
  int b = blockIdx.x, t = threadIdx.x;
  int cnt = 0, rst = 0;
  if (t < NBLK){ cnt = C[b*NBLKP + t]; rst = Rloc[b*NBLKP + t]; }
  lcnt[t] = 0;
  __syncthreads();
  const unsigned int* sl = slab + (size_t)t*ET + rst;   // only touched when cnt>0
  for (int k = 0; k < cnt; ++k){
    unsigned int q = sl[k];
    atomicAdd(&lcnt[q >> 18], 1);
  }
  __syncthreads();
  int rv = lcnt[t];
  lsc[t] = rv;
  __syncthreads();
  for (int o = 1; o < 512; o <<= 1){
    int x = (t >= o) ? lsc[t-o] : 0;
    __syncthreads();
    lsc[t] += x;
    __syncthreads();
  }
  int s0b = s0g[b];
  int d0 = (b < NB_PR) ? b*512 : RN + (b - NB_PR)*512;
  int relEnd = (b < NB_PR) ? RN : NR2;
  int rows = relEnd - d0; if (rows > 512) rows = 512;
  int srcoff = (b < NB_PR) ? 0 : RN;
  int start = lsc[t] - rv;
  lcur[t] = start;
  if (t < rows) rs[d0 + t] = s0b + start;
  __syncthreads();
  for (int k = 0; k < cnt; ++k){
    unsigned int q = sl[k];
    int p = atomicAdd(&lcur[q >> 18], 1);
    col[s0b + p] = (int)(q & 0x3FFFFu) + srcoff;
  }
}

// ---- SpMM: union rows, quarter-wave per dst row, dual output base.
// col via lane-parallel load + shfl; two-tier wave-uniform depth. (R13-validated) ----
__global__ __launch_bounds__(256) void spmmU_k(const int* __restrict__ rs, const int* __restrict__ col,
                                               const unsigned short* __restrict__ Xg,
                                               unsigned short* outA, unsigned short* outB){
  int wv = (int)((blockIdx.x*256 + threadIdx.x) >> 6);
  int lane = threadIdx.x & 63;
  int hl = lane & 15;
  int qb = lane & 48;                  // quarter base lane
  int row = wv*4 + (lane >> 4);        // grid exact: NR2/16 blocks
  int b = rs[row], e = rs[row+1];      // uniform within quarter
  int deg = e - b;
  int dq0 = __shfl(deg, 0), dq1 = __shfl(deg, 16);
  int dq2 = __shfl(deg, 32), dq3 = __shfl(deg, 48);
  int md = max(max(dq0, dq1), max(dq2, dq3));   // wave-uniform trip bound
  float a0 = 0, a1 = 0, a2 = 0, a3 = 0;

  if (md <= 8){                         // wave-uniform fast path (avg md ~8.5)
    if (md > 0){
      int cv = col[b + ((hl < deg) ? hl : 0)];   // lane hl holds col[b+hl]
      uint2v v[8];
      #pragma unroll
      for (int j = 0; j < 8; ++j){
        int ix = __shfl(cv, qb + j, 64);
        ix = ((unsigned)ix < (unsigned)NR2) ? ix : 0;
        v[j] = *(const uint2v*)((const char*)Xg + (((size_t)(unsigned)ix) << 7) + (hl << 3));
      }
      #pragma unroll
      for (int j = 0; j < 8; ++j){
        if (j < deg){
          a0 += bf2f((unsigned short)(v[j].x & 0xFFFFu));
          a1 += bf2f((unsigned short)(v[j].x >> 16));
          a2 += bf2f((unsigned short)(v[j].y & 0xFFFFu));
          a3 += bf2f((unsigned short)(v[j].y >> 16));
        }
      }
    }
  } else {
    for (int i = 0; i < md; i += 16){
      int o = i + hl;
      int cv = col[b + ((o < deg) ? o : 0)];     // lane hl holds col[b+i+hl]
      uint2v v[16];
      #pragma unroll
      for (int j = 0; j < 16; ++j){
        int ix = __shfl(cv, qb + j, 64);
        ix = ((unsigned)ix < (unsigned)NR2) ? ix : 0;
        v[j] = *(const uint2v*)((const char*)Xg + (((size_t)(unsigned)ix) << 7) + (hl << 3));
      }
      #pragma unroll
      for (int j = 0; j < 16; ++j){
        if (i + j < deg){
          a0 += bf2f((unsigned short)(v[j].x & 0xFFFFu));
          a1 += bf2f((unsigned short)(v[j].x >> 16));
          a2 += bf2f((unsigned short)(v[j].y & 0xFFFFu));
          a3 += bf2f((unsigned short)(v[j].y >> 16));
        }
      }
    }
  }
  float nrm = deg > 0 ? rsqrtf((float)deg) : 1.0f;
  uint2v pv;
  pv.x = (unsigned)f2bf(a0*nrm) | ((unsigned)f2bf(a1*nrm) << 16);
  pv.y = (unsigned)f2bf(a2*nrm) | ((unsigned)f2bf(a3*nrm) << 16);
  unsigned short* ob = (row < RN) ? (outA + ((size_t)row << 6))
                                  : (outB + ((size_t)(row - RN) << 6));
  __builtin_nontemporal_store(pv, (uint2v*)ob + hl);
}

// ---- merged GEMM R16: pair+prefetch (R15) + LDS-transposed epilogue.
// Output tile staged in wave-private LDS (no barrier), then written as
// 2 x 16B NT stores/lane = full 128B lines -> kills the 1.69x write
// amplification (86MB vs 51MB ideal) of the old 2B scatter stores. ----
__global__ __launch_bounds__(256) void gemm2m_k(GemmCfg cA, GemmCfg cB){
  __shared__ float ls[128];
  __shared__ unsigned short stg[4][16][72];   // per-wave 16x64 tile, padded stride
  for (int t0 = threadIdx.x; t0 < 128; t0 += 256) ls[t0] = 0.0f;
  __syncthreads();
  int half = (int)(gridDim.x >> 1);
  bool sec = ((int)blockIdx.x >= half);
  const unsigned short* Agg = sec ? cB.Agg : cA.Agg;
  const unsigned short* Xd  = sec ? cB.Xd  : cA.Xd;
  const unsigned short* Wp  = sec ? cB.Wp  : cA.Wp;
  const float* bias         = sec ? cB.bias : cA.bias;
  unsigned short* Hout      = sec ? cB.Hout : cA.Hout;
  float* stats              = sec ? cB.stats : cA.stats;
  int lb = sec ? (int)blockIdx.x - half : (int)blockIdx.x;
  int lane = threadIdx.x & 63;
  int w = (int)(threadIdx.x >> 6);
  int gw = lb*4 + w;
  int nw = half*4;
  int c16 = lane & 15, kg = lane >> 4;

  short8v Bf[2][2][4];
  #pragma unroll
  for (int s = 0; s < 2; ++s)
    #pragma unroll
    for (int t2 = 0; t2 < 2; ++t2)
      #pragma unroll
      for (int c = 0; c < 4; ++c)
        Bf[s][t2][c] = ((const short8v*)Wp)[(((s*2 + t2)*4 + c)*4 + kg)*16 + c16];
  float bc[4];
  #pragma unroll
  for (int c = 0; c < 4; ++c) bc[c] = bias[c*16 + c16];

  const short8v* xd = (const short8v*)Xd;
  const short8v* ag = (const short8v*)Agg;
  const int npair = RN/32;             // 6250 pairs of 16-row tiles
  float ssum[4] = {0,0,0,0}, ssq[4] = {0,0,0,0};

  short8v cur[8], nxt[8];
  int tp = gw;
  if (tp < npair){
    size_t ra = (size_t)(tp*32 + c16);          // tile a rows
    size_t rb = ra + 16;                         // tile b rows
    cur[0] = xd[ra*8 + kg];     cur[1] = xd[ra*8 + 4 + kg];
    cur[2] = ag[ra*8 + kg];     cur[3] = ag[ra*8 + 4 + kg];
    cur[4] = xd[rb*8 + kg];     cur[5] = xd[rb*8 + 4 + kg];
    cur[6] = ag[rb*8 + kg];     cur[7] = ag[rb*8 + 4 + kg];
  }
  for (; tp < npair; ){
    int tn = tp + nw;
    if (tn < npair){                             // prefetch next pair (8 loads)
      size_t ra = (size_t)(tn*32 + c16);
      size_t rb = ra + 16;
      nxt[0] = xd[ra*8 + kg];   nxt[1] = xd[ra*8 + 4 + kg];
      nxt[2] = ag[ra*8 + kg];   nxt[3] = ag[ra*8 + 4 + kg];
      nxt[4] = xd[rb*8 + kg];   nxt[5] = xd[rb*8 + 4 + kg];
      nxt[6] = ag[rb*8 + kg];   nxt[7] = ag[rb*8 + 4 + kg];
    }
    #pragma unroll
    for (int h = 0; h < 2; ++h){                 // tile a (h=0), tile b (h=1)
      f32x4 acc4[4];
      #pragma unroll
      for (int c = 0; c < 4; ++c){ f32x4 z = {bc[c],bc[c],bc[c],bc[c]}; acc4[c] = z; }
      #pragma unroll
      for (int c = 0; c < 4; ++c){
        acc4[c] = __builtin_amdgcn_mfma_f32_16x16x32_bf16(cur[h*4+0], Bf[0][0][c], acc4[c], 0, 0, 0);
        acc4[c] = __builtin_amdgcn_mfma_f32_16x16x32_bf16(cur[h*4+1], Bf[0][1][c], acc4[c], 0, 0, 0);
        acc4[c] = __builtin_amdgcn_mfma_f32_16x16x32_bf16(cur[h*4+2], Bf[1][0][c], acc4[c], 0, 0, 0);
        acc4[c] = __builtin_amdgcn_mfma_f32_16x16x32_bf16(cur[h*4+3], Bf[1][1][c], acc4[c], 0, 0, 0);
      }
      // stage to wave-private LDS (C layout: col=lane&15, row=(lane>>4)*4+r [m89])
      #pragma unroll
      for (int c = 0; c < 4; ++c)
        #pragma unroll
        for (int r = 0; r < 4; ++r){
          float v = acc4[c][r];
          ssum[c] += v; ssq[c] += v*v;
          stg[w][kg*4 + r][c*16 + c16] = f2bf(v);
        }
      // coalesced full-line writeout: 2 x us8 per lane (in-wave LDS ordering)
      size_t rb0 = (size_t)(tp*32 + h*16);
      #pragma unroll
      for (int q = 0; q < 2; ++q){
        int li = q*64 + lane;
        int rr = li >> 3;
        int cc = (li & 7) << 3;
        us8 ov = *(const us8*)&stg[w][rr][cc];
        __builtin_nontemporal_store(ov, (us8*)(Hout + (rb0 + rr)*DIM + cc));
      }
    }
    #pragma unroll
    for (int q = 0; q < 8; ++q) cur[q] = nxt[q];
    tp = tn;
  }
  #pragma unroll
  for (int c = 0; c < 4; ++c){
    atomicAdd(&ls[c*16 + c16], ssum[c]);
    atomicAdd(&ls[64 + c*16 + c16], ssq[c]);
  }
  __syncthreads();
  for (int t0 = threadIdx.x; t0 < 128; t0 += 256) atomicAdd(&stats[t0], ls[t0]);
}

// ---- BN finalize for both halves of a layer ----
__global__ __launch_bounds__(128) void bnfin2_k(const float* stats,
                                                const float* gI, const float* beI, float* acI,
                                                const float* gU, const float* beU, float* acU){
  int t = threadIdx.x, j = t & 63;
  const float* st = (t < 64) ? stats : stats + 128;
  float mu  = st[j]    * (1.0f/RN);
  float var = st[64+j] * (1.0f/RN) - mu*mu;
  float inv = rsqrtf(var + 1e-5f);
  if (t < 64){ float a = gI[j]*inv; acI[j] = a; acI[64+j] = beI[j] - mu*a; }
  else       { float a = gU[j]*inv; acU[j] = a; acU[64+j] = beU[j] - mu*a; }
}

// ---- BN + SiLU in-place over the union buffer (users half then items half) ----
__global__ __launch_bounds__(256) void bnapply2_k(unsigned short* H,
                                                  const float* __restrict__ acU,
                                                  const float* __restrict__ acI, int n8){
  int i = blockIdx.x*256 + threadIdx.x;
  if (i >= n8) return;
  const float* ac = (i < RN*8) ? acU : acI;
  us8 v = ((us8*)H)[i];
  int cb = (i*8) & 63;
  #pragma unroll
  for (int r = 0; r < 8; ++r){
    float x = bf2f(v[r]);
    float y = ac[cb+r]*x + ac[64+cb+r];
    float o = y / (1.0f + expf(-y));
    v[r] = f2bf(o);
  }
  ((us8*)H)[i] = v;
}

// ---- BN + SiLU to d_out; user rows from Hu, item rows from Hi ----
__global__ __launch_bounds__(256) void bnout2_k(const unsigned short* __restrict__ Hu,
                                                const unsigned short* __restrict__ Hi,
                                                const float* __restrict__ acU,
                                                const float* __restrict__ acI,
                                                void* out, const int* __restrict__ flags, int n8){
  int i = blockIdx.x*256 + threadIdx.x;
  if (i >= n8) return;
  int item = (i >= RN*8);
  const float* ac = item ? acI : acU;
  us8 v = item ? ((const us8*)Hi)[i - RN*8] : ((const us8*)Hu)[i];
  int cb = (i*8) & 63;
  float o[8];
  #pragma unroll
  for (int r = 0; r < 8; ++r){
    float x = bf2f(v[r]);
    float y = ac[cb+r]*x + ac[64+cb+r];
    o[r] = y / (1.0f + expf(-y));
  }
  if (flags[0]){
    unsigned short* ob = (unsigned short*)out + (size_t)i*8;
    us8 wv;
    #pragma unroll
    for (int r = 0; r < 8; ++r) wv[r] = f2bf(o[r]);
    __builtin_nontemporal_store(wv, (us8*)ob);
  } else {
    float* ob = (float*)out + (size_t)i*8;
    f32x4 w0 = {o[0],o[1],o[2],o[3]}, w1 = {o[4],o[5],o[6],o[7]};
    __builtin_nontemporal_store(w0, (f32x4*)ob);
    __builtin_nontemporal_store(w1, (f32x4*)ob + 1);
  }
}

extern "C" void kernel_launch(void* const* d_in, const int* in_sizes, int n_in,
                              void* d_out, int out_size, void* d_ws, size_t ws_size,
                              hipStream_t stream){
  (void)in_sizes; (void)n_in; (void)out_size;
  const void* user_emb = d_in[0];
  const void* item_emb = d_in[1];
  const void* go_src   = d_in[18];
  const void* go_dst   = d_in[19];
  const void* back_src = d_in[20];
  const void* back_dst = d_in[21];

  char* ws = (char*)d_ws;
  size_t off = 0;
  auto alloc = [&](size_t bytes) -> void* {
    void* p = ws + off;
    off += (bytes + 255) & ~((size_t)255);
    return p;
  };
  int*   flags  = (int*)  alloc(64);
  float* params = (float*)alloc((size_t)49920*4);
  unsigned short* wpack = (unsigned short*)alloc((size_t)4*8192*2);
  float* bnac   = (float*)alloc(512*4);
  float* stats  = (float*)alloc(512*4);
  int*   Cmat   = (int*)  alloc((size_t)NBB*NBLKP*4);
  int*   Rloc   = (int*)  alloc((size_t)NBB*NBLKP*4);
  int*   Sbuf   = (int*)  alloc(1024*4);
  int*   s0g    = (int*)  alloc(1024*4);
  int*   rs_all = (int*)  alloc((size_t)(NR2+1)*4);
  int*   col_all= (int*)  alloc(((size_t)2*NE + 64)*4);              // +64 pad: deg-0 tail reads
  unsigned short* x1   = (unsigned short*)alloc((size_t)NR2*DIM*2);  // embeddings -> layer-2 agg/out
  unsigned short* x2   = (unsigned short*)alloc((size_t)NR2*DIM*2);  // slab -> layer-1 out (silu'd)
  unsigned short* agg1 = (unsigned short*)alloc((size_t)RN*DIM*2);   // go agg -> layer-2 item out
  if (off > ws_size) return;  // visible as absmax == 5.8125

  unsigned int* slab = (unsigned int*)x2;   // 8MB alias; dead after buildCSR3

  unsigned short* x1u = x1;
  unsigned short* x1i = x1 + (size_t)RN*DIM;
  unsigned short* x2u = x2;
  unsigned short* x2i = x2 + (size_t)RN*DIM;

  const int G8A = (NR2*DIM/8)/256;          // 12500
  const int GSU = NR2/16;                   // 25000 blocks: union spmm, 4 rows/wave

  float* b_go1 = params + 12288;
  float* b_bk1 = params + 24640;
  float* b_go2 = params + 36992;
  float* b_bk2 = params + 49344;
  float* g1u = params + 49408; float* be1u = params + 49472;
  float* g1i = params + 49536; float* be1i = params + 49600;
  float* g2u = params + 49664; float* be2u = params + 49728;
  float* g2i = params + 49792; float* be2i = params + 49856;

  Ptrs16 ps;
  for (int i = 0; i < 16; ++i) ps.p[i] = d_in[2+i];

  detect2_k<<<1,256,0,stream>>>((const unsigned short*)user_emb, (const unsigned int*)go_src,
                                flags, ps, params, stats);
  convpp_k<<<G8A + 128,256,0,stream>>>(user_emb, item_emb, x1, ps, wpack, flags, NR2*DIM/8);

  // ---- CSR build ----
  pass12_k<<<NBLK,256,0,stream>>>((const unsigned int*)go_src, (const unsigned int*)go_dst,
                                  (const unsigned int*)back_src, (const unsigned int*)back_dst,
                                  Cmat, Rloc, slab, flags);
  sizes_k<<<(NBB+3)/4,256,0,stream>>>(Cmat, Sbuf);
  scanS_k<<<1,1024,0,stream>>>(Sbuf, s0g, rs_all);
  buildCSR3_k<<<NBB,512,0,stream>>>(Cmat, Rloc, s0g, slab, rs_all, col_all);

  // ---- layer 1: one union spmm (go rows -> agg1, back rows -> x2u scratch),
  //      one merged gemm (go: agg1+x1i -> x2i; back: x2u+x1u -> x2u in-place) ----
  spmmU_k<<<GSU,256,0,stream>>>(rs_all, col_all, x1, agg1, x2u);
  {
    GemmCfg go1{agg1, x1i, wpack + 0*8192, b_go1, x2i, stats + 0};
    GemmCfg bk1{x2u,  x1u, wpack + 1*8192, b_bk1, x2u, stats + 128};
    gemm2m_k<<<1024,256,0,stream>>>(go1, bk1);
  }
  bnfin2_k<<<1,128,0,stream>>>(stats + 0, g1i, be1i, bnac + 0, g1u, be1u, bnac + 128);
  bnapply2_k<<<G8A,256,0,stream>>>(x2, bnac + 128, bnac + 0, NR2*DIM/8);

  // ---- layer 2: union spmm from silu'd x2 -> agg2 = x1 (union),
  //      merged gemm (go: x1lo+x2i -> agg1; back: x1hi+x2u -> x1hi in-place) ----
  spmmU_k<<<GSU,256,0,stream>>>(rs_all, col_all, x2, x1u, x1i);
  {
    GemmCfg go2{x1u, x2i, wpack + 2*8192, b_go2, agg1, stats + 256};
    GemmCfg bk2{x1i, x2u, wpack + 3*8192, b_bk2, x1i,  stats + 384};
    gemm2m_k<<<1024,256,0,stream>>>(go2, bk2);
  }
  bnfin2_k<<<1,128,0,stream>>>(stats + 256, g2i, be2i, bnac + 256, g2u, be2u, bnac + 384);
  bnout2_k<<<G8A,256,0,stream>>>(x1i, agg1, bnac + 384, bnac + 256, d_out, flags, NR2*DIM/8);
}

// Round 17
// 322.656 us; speedup vs baseline: 1.1581x; 1.0253x over previous
//
#include <hip/hip_runtime.h>
#include <cstdint>
#include <cstddef>

#define RN 200000   // nodes per side (NU == NI)
#define NR2 400000  // both sides
#define DIM 64
#define NE 1000000  // edges per relation
#define NB_PR 391   // buckets per relation (512 rows each)
#define NBB 782     // total buckets (go: 0..390, back: 391..781)
#define ET 4096     // edges per sort block
#define NBLK 489    // ceil(2*NE / ET)
#define NBLKP 512   // padded row length of C/Rloc (bucket-major)

typedef __attribute__((ext_vector_type(8))) short short8v;   // 8 x bf16 (4 VGPR)
typedef __attribute__((ext_vector_type(4))) float f32x4;
typedef __attribute__((ext_vector_type(8))) unsigned short us8;
typedef __attribute__((ext_vector_type(2))) unsigned int uint2v;

struct Ptrs16 { const void* p[16]; };

struct GemmCfg {
  const unsigned short* Agg;   // may alias Hout (in-place) -> no __restrict
  const unsigned short* Xd;
  const unsigned short* Wp;
  const float* bias;
  unsigned short* Hout;
  float* stats;
};

__device__ __forceinline__ float bf2f(unsigned short u){
  unsigned int x = ((unsigned int)u) << 16;
  return __builtin_bit_cast(float, x);
}
__device__ __forceinline__ unsigned short f2bf(float f){
  unsigned int x = __builtin_bit_cast(unsigned int, f);
  unsigned int r = x + 0x7fffu + ((x >> 16) & 1u);   // RNE
  return (unsigned short)(r >> 16);
}

// ---- dtype sniff + small-param convert + stats zero (single block) ----
__global__ __launch_bounds__(256) void detect2_k(const unsigned short* emb,
                                                 const unsigned int* esrc,
                                                 int* flags, Ptrs16 ps,
                                                 float* params, float* stats){
  __shared__ int cnt0, cnt1, sf0;
  int t = threadIdx.x;
  if (t == 0){ cnt0 = 0; cnt1 = 0; }
  __syncthreads();
  int c0 = 0, c1 = 0;
  #pragma unroll
  for (int s = 0; s < 4; ++s){
    int i = (t*4 + s) * 14;
    float af = fabsf(bf2f(emb[i]));
    if (af > 0.0009765625f && af < 32.0f) c0++;
    int e = t*4 + s;
    if (esrc[2*e + 1] != 0u) c1++;
  }
  atomicAdd(&cnt0, c0); atomicAdd(&cnt1, c1);
  __syncthreads();
  if (t == 0){
    int f0 = (cnt0 > 512) ? 1 : 0;
    int f1 = (cnt1 < 512) ? 1 : 0;
    flags[0] = f0; flags[1] = f1; sf0 = f0;
  }
  __syncthreads();
  int f0 = sf0;
  const int aidx[12] = {1,3,5,7,8,9,10,11,12,13,14,15};
  const int aoff[12] = {12288,24640,36992,49344,49408,49472,49536,49600,49664,49728,49792,49856};
  for (int base = t; base < 768; base += 256){
    int a = base >> 6, j = base & 63;
    const void* p = ps.p[aidx[a]];
    params[aoff[a] + j] = f0 ? bf2f(((const unsigned short*)p)[j]) : ((const float*)p)[j];
  }
  for (int z = t; z < 512; z += 256) stats[z] = 0.0f;
}

// ---- fused: blocks [0,128) prepack the 4 weight mats into MFMA frag order;
//      blocks [128, 128+n8/256) canonicalize embeddings into union bf16 x1 ----
__global__ __launch_bounds__(256) void convpp_k(const void* uin, const void* iin,
                                                unsigned short* __restrict__ out,
                                                Ptrs16 ps, unsigned short* __restrict__ wpack,
                                                const int* flags, int n8){
  int bid = blockIdx.x;
  if (bid < 128){
    int i = bid*256 + threadIdx.x;
    int m = i >> 13, f = i & 8191;
    int r   = f & 7;
    int c16 = (f >> 3) & 15;
    int kg  = (f >> 7) & 3;
    int c   = (f >> 9) & 3;
    int t2  = (f >> 11) & 1;
    int s   = (f >> 12) & 1;
    int k = s*64 + t2*32 + kg*8 + r;
    int j = k*DIM + c*16 + c16;
    const void* wp = ps.p[m*2];        // W_go1, W_back1, W_go2, W_back2
    float v = flags[0] ? bf2f(((const unsigned short*)wp)[j]) : ((const float*)wp)[j];
    wpack[i] = f2bf(v);
    return;
  }
  int i = (bid - 128)*256 + threadIdx.x;
  if (i >= n8) return;
  int item = (i >= RN*8);
  const void* in = item ? iin : uin;
  int li = item ? i - RN*8 : i;
  us8 o;
  if (flags[0]){
    o = ((const us8*)in)[li];
  } else {
    const float* f = (const float*)in + (size_t)li*8;
    #pragma unroll
    for (int r = 0; r < 8; ++r) o[r] = f2bf(f[r]);
  }
  ((us8*)out)[i] = o;
}

// ==== CSR build: single-read merged histogram + scatter (validated R11) ====
__global__ __launch_bounds__(256) void pass12_k(const unsigned int* go_src, const unsigned int* go_dst,
                                                const unsigned int* back_src, const unsigned int* back_dst,
                                                int* __restrict__ C, int* __restrict__ Rloc,
                                                unsigned int* __restrict__ slab, const int* flags){
  __shared__ unsigned int spk[ET];      // 16KB: src | row_in_bucket<<18
  __shared__ unsigned short sbk[ET];    // 8KB: bucket id (0xFFFF = invalid)
  __shared__ int h[1024];               // histogram -> cursors
  __shared__ int ps[256];
  int blk = blockIdx.x, t = threadIdx.x;
  #pragma unroll
  for (int q = 0; q < 4; ++q) h[t + q*256] = 0;
  __syncthreads();
  int i64 = flags[1];
  int e0 = blk*ET;
  #pragma unroll
  for (int j = 0; j < 16; ++j){
    int e = e0 + j*256 + t;
    int li = j*256 + t;
    if (e < 2*NE){
      int rel = e >= NE;
      int ei = rel ? e - NE : e;
      const unsigned int* pd = rel ? back_dst : go_dst;
      const unsigned int* psr = rel ? back_src : go_src;
      int d  = i64 ? (int)pd[2*ei]  : (int)pd[ei];
      int sc = i64 ? (int)psr[2*ei] : (int)psr[ei];
      int b = (rel ? NB_PR : 0) + (d >> 9);
      spk[li] = (unsigned)sc | ((unsigned)(d & 511) << 18);
      sbk[li] = (unsigned short)b;
      atomicAdd(&h[b], 1);
    } else {
      sbk[li] = 0xFFFFu;
    }
  }
  __syncthreads();
  int c4[4], p4[4]; int s = 0;
  #pragma unroll
  for (int q = 0; q < 4; ++q){ c4[q] = h[t*4 + q]; p4[q] = s; s += c4[q]; }
  ps[t] = s;
  __syncthreads();
  for (int o = 1; o < 256; o <<= 1){
    int x = (t >= o) ? ps[t-o] : 0;
    __syncthreads();
    ps[t] += x;
    __syncthreads();
  }
  int base = (t > 0) ? ps[t-1] : 0;
  #pragma unroll
  for (int q = 0; q < 4; ++q){
    int b = t*4 + q;
    if (b < NBB){
      C[b*NBLKP + blk]    = c4[q];
      Rloc[b*NBLKP + blk] = base + p4[q];
    }
  }
  __syncthreads();                       // scan reads done; reuse h as cursors
  #pragma unroll
  for (int q = 0; q < 4; ++q){
    int b = t*4 + q;
    h[b] = base + p4[q];
  }
  __syncthreads();
  #pragma unroll
  for (int j = 0; j < 16; ++j){
    int li = j*256 + t;
    unsigned short b = sbk[li];
    if (b != 0xFFFFu){
      int pos = atomicAdd(&h[b], 1);
      slab[(size_t)blk*ET + pos] = spk[li];
    }
  }
}

__global__ __launch_bounds__(256) void sizes_k(const int* __restrict__ C, int* __restrict__ S){
  int w = blockIdx.x*4 + (threadIdx.x >> 6);
  int lane = threadIdx.x & 63;
  if (w >= NBB) return;
  int sum = 0;
  for (int k = lane; k < NBLK; k += 64) sum += C[w*NBLKP + k];
  #pragma unroll
  for (int o = 32; o > 0; o >>= 1) sum += __shfl_down(sum, o, 64);
  if (lane == 0) S[w] = sum;
}

__global__ __launch_bounds__(1024) void scanS_k(const int* __restrict__ S, int* __restrict__ s0,
                                                int* __restrict__ rs){
  __shared__ int sh[1024];
  int t = threadIdx.x;
  int v = (t < NBB) ? S[t] : 0;
  sh[t] = v;
  __syncthreads();
  for (int o = 1; o < 1024; o <<= 1){
    int x = (t >= o) ? sh[t-o] : 0;
    __syncthreads();
    sh[t] += x;
    __syncthreads();
  }
  if (t < NBB) s0[t] = sh[t] - v;
  if (t == NBB-1){ s0[NBB] = sh[t]; rs[NR2] = 2*NE; }
}

// ---- per-RUN iteration (no binary search; validated R12). Thread t owns run t.
// col written in UNION space (+RN for back-relation sources = items) ----
__global__ __launch_bounds__(512) void buildCSR3_k(const int* __restrict__ C,
                                                   const int* __restrict__ Rloc,
                                                   const int* __restrict__ s0g,
                                                   const unsigned int* __restrict__ slab,
                                                   int* __restrict__ rs, int* __restrict__ col){
  __shared__ int lcnt[512], lsc[512], lcur[512];
  int b = blockIdx.x, t = threadIdx.x;
  int cnt = 0, rst = 0;
  if (t < NBLK){ cnt = C[b*NBLKP + t]; rst = Rloc[b*NBLKP + t]; }
  lcnt[t] = 0;
  __syncthreads();
  const unsigned int* sl = slab + (size_t)t*ET + rst;   // only touched when cnt>0
  for (int k = 0; k < cnt; ++k){
    unsigned int q = sl[k];
    atomicAdd(&lcnt[q >> 18], 1);
  }
  __syncthreads();
  int rv = lcnt[t];
  lsc[t] = rv;
  __syncthreads();
  for (int o = 1; o < 512; o <<= 1){
    int x = (t >= o) ? lsc[t-o] : 0;
    __syncthreads();
    lsc[t] += x;
    __syncthreads();
  }
  int s0b = s0g[b];
  int d0 = (b < NB_PR) ? b*512 : RN + (b - NB_PR)*512;
  int relEnd = (b < NB_PR) ? RN : NR2;
  int rows = relEnd - d0; if (rows > 512) rows = 512;
  int srcoff = (b < NB_PR) ? 0 : RN;
  int start = lsc[t] - rv;
  lcur[t] = start;
  if (t < rows) rs[d0 + t] = s0b + start;
  __syncthreads();
  for (int k = 0; k < cnt; ++k){
    unsigned int q = sl[k];
    int p = atomicAdd(&lcur[q >> 18], 1);
    col[s0b + p] = (int)(q & 0x3FFFFu) + srcoff;
  }
}

// ---- SpMM R17: EIGHTH-WAVE per dst row. 8 lanes x 16 B (us8, full row) per
// row, 8 rows/wave, 16-deep batches -> each gather inst covers 8 lines (2x R13).
// col via lane-parallel load + shfl; two-tier wave-uniform depth. ----
__global__ __launch_bounds__(256) void spmmU_k(const int* __restrict__ rs, const int* __restrict__ col,
                                               const unsigned short* __restrict__ Xg,
                                               unsigned short* outA, unsigned short* outB){
  int wv = (int)((blockIdx.x*256 + threadIdx.x) >> 6);
  int lane = threadIdx.x & 63;
  int el = lane & 7;                   // lane within eighth
  int eb = lane & 56;                  // eighth base lane
  int row = wv*8 + (lane >> 3);        // grid exact: NR2/32 blocks
  int b = rs[row], e = rs[row+1];      // uniform within eighth
  int deg = e - b;
  int md = deg;                        // wave max (deg uniform within eighth)
  #pragma unroll
  for (int o = 8; o < 64; o <<= 1) md = max(md, __shfl_xor(md, o, 64));
  float ac[8];
  #pragma unroll
  for (int r = 0; r < 8; ++r) ac[r] = 0.0f;

  if (md <= 8){                         // wave-uniform fast path (avg md ~9)
    if (md > 0){
      int cv = col[b + ((el < deg) ? el : 0)];   // lane el holds col[b+el]
      us8 v[8];
      #pragma unroll
      for (int j = 0; j < 8; ++j){
        int ix = __shfl(cv, eb + j, 64);
        ix = ((unsigned)ix < (unsigned)NR2) ? ix : 0;
        v[j] = *(const us8*)((const char*)Xg + (((size_t)(unsigned)ix) << 7) + (el << 4));
      }
      #pragma unroll
      for (int j = 0; j < 8; ++j){
        if (j < deg){
          #pragma unroll
          for (int r = 0; r < 8; ++r) ac[r] += bf2f(v[j][r]);
        }
      }
    }
  } else {
    for (int i = 0; i < md; i += 16){
      int o0 = i + el, o1 = i + 8 + el;
      int cv0 = col[b + ((o0 < deg) ? o0 : 0)];
      int cv1 = col[b + ((o1 < deg) ? o1 : 0)];
      us8 v[16];
      #pragma unroll
      for (int j = 0; j < 8; ++j){
        int ix = __shfl(cv0, eb + j, 64);
        ix = ((unsigned)ix < (unsigned)NR2) ? ix : 0;
        v[j] = *(const us8*)((const char*)Xg + (((size_t)(unsigned)ix) << 7) + (el << 4));
      }
      #pragma unroll
      for (int j = 0; j < 8; ++j){
        int ix = __shfl(cv1, eb + j, 64);
        ix = ((unsigned)ix < (unsigned)NR2) ? ix : 0;
        v[8+j] = *(const us8*)((const char*)Xg + (((size_t)(unsigned)ix) << 7) + (el << 4));
      }
      #pragma unroll
      for (int j = 0; j < 16; ++j){
        if (i + j < deg){
          #pragma unroll
          for (int r = 0; r < 8; ++r) ac[r] += bf2f(v[j][r]);
        }
      }
    }
  }
  float nrm = deg > 0 ? rsqrtf((float)deg) : 1.0f;
  us8 pv;
  #pragma unroll
  for (int r = 0; r < 8; ++r) pv[r] = f2bf(ac[r]*nrm);
  unsigned short* ob = (row < RN) ? (outA + ((size_t)row << 6))
                                  : (outB + ((size_t)(row - RN) << 6));
  __builtin_nontemporal_store(pv, (us8*)ob + el);
}

// ---- merged GEMM: pair+prefetch + LDS full-line epilogue (validated R16) ----
__global__ __launch_bounds__(256) void gemm2m_k(GemmCfg cA, GemmCfg cB){
  __shared__ float ls[128];
  __shared__ unsigned short stg[4][16][72];   // per-wave 16x64 tile, padded stride
  for (int t0 = threadIdx.x; t0 < 128; t0 += 256) ls[t0] = 0.0f;
  __syncthreads();
  int half = (int)(gridDim.x >> 1);
  bool sec = ((int)blockIdx.x >= half);
  const unsigned short* Agg = sec ? cB.Agg : cA.Agg;
  const unsigned short* Xd  = sec ? cB.Xd  : cA.Xd;
  const unsigned short* Wp  = sec ? cB.Wp  : cA.Wp;
  const float* bias         = sec ? cB.bias : cA.bias;
  unsigned short* Hout      = sec ? cB.Hout : cA.Hout;
  float* stats              = sec ? cB.stats : cA.stats;
  int lb = sec ? (int)blockIdx.x - half : (int)blockIdx.x;
  int lane = threadIdx.x & 63;
  int w = (int)(threadIdx.x >> 6);
  int gw = lb*4 + w;
  int nw = half*4;
  int c16 = lane & 15, kg = lane >> 4;

  short8v Bf[2][2][4];
  #pragma unroll
  for (int s = 0; s < 2; ++s)
    #pragma unroll
    for (int t2 = 0; t2 < 2; ++t2)
      #pragma unroll
      for (int c = 0; c < 4; ++c)
        Bf[s][t2][c] = ((const short8v*)Wp)[(((s*2 + t2)*4 + c)*4 + kg)*16 + c16];
  float bc[4];
  #pragma unroll
  for (int c = 0; c < 4; ++c) bc[c] = bias[c*16 + c16];

  const short8v* xd = (const short8v*)Xd;
  const short8v* ag = (const short8v*)Agg;
  const int npair = RN/32;             // 6250 pairs of 16-row tiles
  float ssum[4] = {0,0,0,0}, ssq[4] = {0,0,0,0};

  short8v cur[8], nxt[8];
  int tp = gw;
  if (tp < npair){
    size_t ra = (size_t)(tp*32 + c16);          // tile a rows
    size_t rb = ra + 16;                         // tile b rows
    cur[0] = xd[ra*8 + kg];     cur[1] = xd[ra*8 + 4 + kg];
    cur[2] = ag[ra*8 + kg];     cur[3] = ag[ra*8 + 4 + kg];
    cur[4] = xd[rb*8 + kg];     cur[5] = xd[rb*8 + 4 + kg];
    cur[6] = ag[rb*8 + kg];     cur[7] = ag[rb*8 + 4 + kg];
  }
  for (; tp < npair; ){
    int tn = tp + nw;
    if (tn < npair){                             // prefetch next pair (8 loads)
      size_t ra = (size_t)(tn*32 + c16);
      size_t rb = ra + 16;
      nxt[0] = xd[ra*8 + kg];   nxt[1] = xd[ra*8 + 4 + kg];
      nxt[2] = ag[ra*8 + kg];   nxt[3] = ag[ra*8 + 4 + kg];
      nxt[4] = xd[rb*8 + kg];   nxt[5] = xd[rb*8 + 4 + kg];
      nxt[6] = ag[rb*8 + kg];   nxt[7] = ag[rb*8 + 4 + kg];
    }
    #pragma unroll
    for (int h = 0; h < 2; ++h){                 // tile a (h=0), tile b (h=1)
      f32x4 acc4[4];
      #pragma unroll
      for (int c = 0; c < 4; ++c){ f32x4 z = {bc[c],bc[c],bc[c],bc[c]}; acc4[c] = z; }
      #pragma unroll
      for (int c = 0; c < 4; ++c){
        acc4[c] = __builtin_amdgcn_mfma_f32_16x16x32_bf16(cur[h*4+0], Bf[0][0][c], acc4[c], 0, 0, 0);
        acc4[c] = __builtin_amdgcn_mfma_f32_16x16x32_bf16(cur[h*4+1], Bf[0][1][c], acc4[c], 0, 0, 0);
        acc4[c] = __builtin_amdgcn_mfma_f32_16x16x32_bf16(cur[h*4+2], Bf[1][0][c], acc4[c], 0, 0, 0);
        acc4[c] = __builtin_amdgcn_mfma_f32_16x16x32_bf16(cur[h*4+3], Bf[1][1][c], acc4[c], 0, 0, 0);
      }
      // stage to wave-private LDS (C layout: col=lane&15, row=(lane>>4)*4+r [m89])
      #pragma unroll
      for (int c = 0; c < 4; ++c)
        #pragma unroll
        for (int r = 0; r < 4; ++r){
          float v = acc4[c][r];
          ssum[c] += v; ssq[c] += v*v;
          stg[w][kg*4 + r][c*16 + c16] = f2bf(v);
        }
      // coalesced full-line writeout: 2 x us8 per lane (in-wave LDS ordering)
      size_t rb0 = (size_t)(tp*32 + h*16);
      #pragma unroll
      for (int q = 0; q < 2; ++q){
        int li = q*64 + lane;
        int rr = li >> 3;
        int cc = (li & 7) << 3;
        us8 ov = *(const us8*)&stg[w][rr][cc];
        __builtin_nontemporal_store(ov, (us8*)(Hout + (rb0 + rr)*DIM + cc));
      }
    }
    #pragma unroll
    for (int q = 0; q < 8; ++q) cur[q] = nxt[q];
    tp = tn;
  }
  #pragma unroll
  for (int c = 0; c < 4; ++c){
    atomicAdd(&ls[c*16 + c16], ssum[c]);
    atomicAdd(&ls[64 + c*16 + c16], ssq[c]);
  }
  __syncthreads();
  for (int t0 = threadIdx.x; t0 < 128; t0 += 256) atomicAdd(&stats[t0], ls[t0]);
}

// ---- BN + SiLU in-place over the union buffer; BN coeffs computed per block
// from stats (folds the old bnfin launch). statsI/statsU: 128 floats each. ----
__global__ __launch_bounds__(256) void bnapply2_k(unsigned short* H,
                                                  const float* __restrict__ stats,
                                                  const float* __restrict__ gI, const float* __restrict__ beI,
                                                  const float* __restrict__ gU, const float* __restrict__ beU,
                                                  int n8){
  __shared__ float lac[256];   // [0..64)=aU [64..128)=cU [128..192)=aI [192..256)=cI
  int t = threadIdx.x;
  if (t < 128){
    int usr = (t < 64);
    int j = t & 63;
    const float* st = usr ? stats + 128 : stats;      // items at +0, users at +128
    float mu  = st[j]    * (1.0f/RN);
    float var = st[64+j] * (1.0f/RN) - mu*mu;
    float inv = rsqrtf(var + 1e-5f);
    float g  = usr ? gU[j]  : gI[j];
    float be = usr ? beU[j] : beI[j];
    float a = g * inv;
    int o = usr ? 0 : 128;
    lac[o + j] = a;
    lac[o + 64 + j] = be - mu*a;
  }
  __syncthreads();
  int i = blockIdx.x*256 + t;
  if (i >= n8) return;
  const float* ac = (i < RN*8) ? lac : lac + 128;
  us8 v = ((us8*)H)[i];
  int cb = (i*8) & 63;
  #pragma unroll
  for (int r = 0; r < 8; ++r){
    float x = bf2f(v[r]);
    float y = ac[cb+r]*x + ac[64+cb+r];
    float o = y / (1.0f + expf(-y));
    v[r] = f2bf(o);
  }
  ((us8*)H)[i] = v;
}

// ---- BN + SiLU to d_out; coeffs from stats per block (folds bnfin) ----
__global__ __launch_bounds__(256) void bnout2_k(const unsigned short* __restrict__ Hu,
                                                const unsigned short* __restrict__ Hi,
                                                const float* __restrict__ stats,
                                                const float* __restrict__ gI, const float* __restrict__ beI,
                                                const float* __restrict__ gU, const float* __restrict__ beU,
                                                void* out, const int* __restrict__ flags, int n8){
  __shared__ float lac[256];
  int t = threadIdx.x;
  if (t < 128){
    int usr = (t < 64);
    int j = t & 63;
    const float* st = usr ? stats + 128 : stats;
    float mu  = st[j]    * (1.0f/RN);
    float var = st[64+j] * (1.0f/RN) - mu*mu;
    float inv = rsqrtf(var + 1e-5f);
    float g  = usr ? gU[j]  : gI[j];
    float be = usr ? beU[j] : beI[j];
    float a = g * inv;
    int o = usr ? 0 : 128;
    lac[o + j] = a;
    lac[o + 64 + j] = be - mu*a;
  }
  __syncthreads();
  int i = blockIdx.x*256 + t;
  if (i >= n8) return;
  int item = (i >= RN*8);
  const float* ac = item ? lac + 128 : lac;
  us8 v = item ? ((const us8*)Hi)[i - RN*8] : ((const us8*)Hu)[i];
  int cb = (i*8) & 63;
  float o[8];
  #pragma unroll
  for (int r = 0; r < 8; ++r){
    float x = bf2f(v[r]);
    float y = ac[cb+r]*x + ac[64+cb+r];
    o[r] = y / (1.0f + expf(-y));
  }
  if (flags[0]){
    unsigned short* ob = (unsigned short*)out + (size_t)i*8;
    us8 wv;
    #pragma unroll
    for (int r = 0; r < 8; ++r) wv[r] = f2bf(o[r]);
    __builtin_nontemporal_store(wv, (us8*)ob);
  } else {
    float* ob = (float*)out + (size_t)i*8;
    f32x4 w0 = {o[0],o[1],o[2],o[3]}, w1 = {o[4],o[5],o[6],o[7]};
    __builtin_nontemporal_store(w0, (f32x4*)ob);
    __builtin_nontemporal_store(w1, (f32x4*)ob + 1);
  }
}

extern "C" void kernel_launch(void* const* d_in, const int* in_sizes, int n_in,
                              void* d_out, int out_size, void* d_ws, size_t ws_size,
                              hipStream_t stream){
  (void)in_sizes; (void)n_in; (void)out_size;
  const void* user_emb = d_in[0];
  const void* item_emb = d_in[1];
  const void* go_src   = d_in[18];
  const void* go_dst   = d_in[19];
  const void* back_src = d_in[20];
  const void* back_dst = d_in[21];

  char* ws = (char*)d_ws;
  size_t off = 0;
  auto alloc = [&](size_t bytes) -> void* {
    void* p = ws + off;
    off += (bytes + 255) & ~((size_t)255);
    return p;
  };
  int*   flags  = (int*)  alloc(64);
  float* params = (float*)alloc((size_t)49920*4);
  unsigned short* wpack = (unsigned short*)alloc((size_t)4*8192*2);
  float* stats  = (float*)alloc(512*4);
  int*   Cmat   = (int*)  alloc((size_t)NBB*NBLKP*4);
  int*   Rloc   = (int*)  alloc((size_t)NBB*NBLKP*4);
  int*   Sbuf   = (int*)  alloc(1024*4);
  int*   s0g    = (int*)  alloc(1024*4);
  int*   rs_all = (int*)  alloc((size_t)(NR2+1)*4);
  int*   col_all= (int*)  alloc(((size_t)2*NE + 64)*4);              // +64 pad: deg-0 tail reads
  unsigned short* x1   = (unsigned short*)alloc((size_t)NR2*DIM*2);  // embeddings -> layer-2 agg/out
  unsigned short* x2   = (unsigned short*)alloc((size_t)NR2*DIM*2);  // slab -> layer-1 out (silu'd)
  unsigned short* agg1 = (unsigned short*)alloc((size_t)RN*DIM*2);   // go agg -> layer-2 item out
  if (off > ws_size) return;  // visible as absmax == 5.8125

  unsigned int* slab = (unsigned int*)x2;   // 8MB alias; dead after buildCSR3

  unsigned short* x1u = x1;
  unsigned short* x1i = x1 + (size_t)RN*DIM;
  unsigned short* x2u = x2;
  unsigned short* x2i = x2 + (size_t)RN*DIM;

  const int G8A = (NR2*DIM/8)/256;          // 12500
  const int GSU = NR2/32;                   // 12500 blocks: union spmm, 8 rows/wave

  float* b_go1 = params + 12288;
  float* b_bk1 = params + 24640;
  float* b_go2 = params + 36992;
  float* b_bk2 = params + 49344;
  float* g1u = params + 49408; float* be1u = params + 49472;
  float* g1i = params + 49536; float* be1i = params + 49600;
  float* g2u = params + 49664; float* be2u = params + 49728;
  float* g2i = params + 49792; float* be2i = params + 49856;

  Ptrs16 ps;
  for (int i = 0; i < 16; ++i) ps.p[i] = d_in[2+i];

  detect2_k<<<1,256,0,stream>>>((const unsigned short*)user_emb, (const unsigned int*)go_src,
                                flags, ps, params, stats);
  convpp_k<<<G8A + 128,256,0,stream>>>(user_emb, item_emb, x1, ps, wpack, flags, NR2*DIM/8);

  // ---- CSR build ----
  pass12_k<<<NBLK,256,0,stream>>>((const unsigned int*)go_src, (const unsigned int*)go_dst,
                                  (const unsigned int*)back_src, (const unsigned int*)back_dst,
                                  Cmat, Rloc, slab, flags);
  sizes_k<<<(NBB+3)/4,256,0,stream>>>(Cmat, Sbuf);
  scanS_k<<<1,1024,0,stream>>>(Sbuf, s0g, rs_all);
  buildCSR3_k<<<NBB,512,0,stream>>>(Cmat, Rloc, s0g, slab, rs_all, col_all);

  // ---- layer 1: one union spmm (go rows -> agg1, back rows -> x2u scratch),
  //      one merged gemm (go: agg1+x1i -> x2i; back: x2u+x1u -> x2u in-place) ----
  spmmU_k<<<GSU,256,0,stream>>>(rs_all, col_all, x1, agg1, x2u);
  {
    GemmCfg go1{agg1, x1i, wpack + 0*8192, b_go1, x2i, stats + 0};
    GemmCfg bk1{x2u,  x1u, wpack + 1*8192, b_bk1, x2u, stats + 128};
    gemm2m_k<<<1024,256,0,stream>>>(go1, bk1);
  }
  bnapply2_k<<<G8A,256,0,stream>>>(x2, stats, g1i, be1i, g1u, be1u, NR2*DIM/8);

  // ---- layer 2: union spmm from silu'd x2 -> agg2 = x1 (union),
  //      merged gemm (go: x1lo+x2i -> agg1; back: x1hi+x2u -> x1hi in-place) ----
  spmmU_k<<<GSU,256,0,stream>>>(rs_all, col_all, x2, x1u, x1i);
  {
    GemmCfg go2{x1u, x2i, wpack + 2*8192, b_go2, agg1, stats + 256};
    GemmCfg bk2{x1i, x2u, wpack + 3*8192, b_bk2, x1i,  stats + 384};
    gemm2m_k<<<1024,256,0,stream>>>(go2, bk2);
  }
  bnout2_k<<<G8A,256,0,stream>>>(x1i, agg1, stats + 256, g2i, be2i, g2u, be2u,
                                 d_out, flags, NR2*DIM/8);
}